// Round 2
// baseline (376.591 us; speedup 1.0000x reference)
//
#include <hip/hip_runtime.h>

// ---------------- CSR build ----------------

__global__ void k_count(const int* __restrict__ dst, int* __restrict__ cnt, int E) {
    int e = blockIdx.x * blockDim.x + threadIdx.x;
    if (e < E) atomicAdd(&cnt[dst[e]], 1);
}

// One block, 1024 threads: exclusive scan of cnt[0..n) -> rowoff[0..n], cursor copy,
// dinv = rsqrt(cnt+1).
#define SCAN_CHUNK 20
__global__ void k_scan(const int* __restrict__ cnt, int* __restrict__ rowoff,
                       int* __restrict__ cursor, float* __restrict__ dinv, int n) {
    __shared__ int psum[1024];
    int t = threadIdx.x;
    int base = t * SCAN_CHUNK;
    int vals[SCAN_CHUNK];
    int local = 0;
#pragma unroll
    for (int i = 0; i < SCAN_CHUNK; ++i) {
        int idx = base + i;
        vals[i] = (idx < n) ? cnt[idx] : 0;
        local += vals[i];
    }
    psum[t] = local;
    __syncthreads();
    // Hillis-Steele inclusive scan over 1024 partials
    for (int off = 1; off < 1024; off <<= 1) {
        int v = 0;
        if (t >= off) v = psum[t - off];
        __syncthreads();
        if (t >= off) psum[t] += v;
        __syncthreads();
    }
    int run = (t > 0) ? psum[t - 1] : 0;
#pragma unroll
    for (int i = 0; i < SCAN_CHUNK; ++i) {
        int idx = base + i;
        if (idx < n) {
            rowoff[idx] = run;
            cursor[idx] = run;
            dinv[idx]   = rsqrtf((float)(vals[i] + 1));
            run += vals[i];
        }
    }
    if (t == 1023) rowoff[n] = psum[1023];
}

__global__ void k_fill(const int* __restrict__ src, const int* __restrict__ dst,
                       int* __restrict__ cursor, int* __restrict__ col, int E) {
    int e = blockIdx.x * blockDim.x + threadIdx.x;
    if (e < E) {
        int pos = atomicAdd(&cursor[dst[e]], 1);
        col[pos] = src[e];
    }
}

// ---------------- GEMM (fp32, SIMT) ----------------
// C[M,N] = A[M,K] @ W[K,N]; BM=BN=64, BK=32, 256 threads, 4x4 micro-tile.
template<int BM, int BN, int BK>
__global__ void k_gemm(const float* __restrict__ A, const float* __restrict__ W,
                       float* __restrict__ C, int M, int K, int N) {
    __shared__ float As[BK][BM + 4];
    __shared__ float Bs[BK][BN + 4];
    const int tid = threadIdx.x;
    const int tx = tid & 15;   // col group
    const int ty = tid >> 4;   // row group
    const int bm = blockIdx.y * BM;
    const int bn = blockIdx.x * BN;

    float acc[4][4] = {};

    for (int k0 = 0; k0 < K; k0 += BK) {
        // A tile: BM x BK floats, float4 loads along K
#pragma unroll
        for (int i = 0; i < (BM * BK) / (256 * 4); ++i) {
            int idx = (tid + i * 256) * 4;
            int m = idx / BK, kk = idx % BK;
            int row = bm + m;
            float4 v = make_float4(0.f, 0.f, 0.f, 0.f);
            if (row < M) v = *reinterpret_cast<const float4*>(&A[(size_t)row * K + k0 + kk]);
            As[kk + 0][m] = v.x; As[kk + 1][m] = v.y;
            As[kk + 2][m] = v.z; As[kk + 3][m] = v.w;
        }
        // B tile: BK x BN floats
#pragma unroll
        for (int i = 0; i < (BK * BN) / (256 * 4); ++i) {
            int idx = (tid + i * 256) * 4;
            int kk = idx / BN, nn = idx % BN;
            float4 v = *reinterpret_cast<const float4*>(&W[(size_t)(k0 + kk) * N + bn + nn]);
            Bs[kk][nn + 0] = v.x; Bs[kk][nn + 1] = v.y;
            Bs[kk][nn + 2] = v.z; Bs[kk][nn + 3] = v.w;
        }
        __syncthreads();
#pragma unroll
        for (int kk = 0; kk < BK; ++kk) {
            float a[4], b[4];
#pragma unroll
            for (int i = 0; i < 4; ++i) a[i] = As[kk][ty * 4 + i];
#pragma unroll
            for (int j = 0; j < 4; ++j) b[j] = Bs[kk][tx * 4 + j];
#pragma unroll
            for (int i = 0; i < 4; ++i)
#pragma unroll
                for (int j = 0; j < 4; ++j) acc[i][j] += a[i] * b[j];
        }
        __syncthreads();
    }

#pragma unroll
    for (int i = 0; i < 4; ++i) {
        int row = bm + ty * 4 + i;
        if (row < M) {
            float4 v = make_float4(acc[i][0], acc[i][1], acc[i][2], acc[i][3]);
            *reinterpret_cast<float4*>(&C[(size_t)row * N + bn + tx * 4]) = v;
        }
    }
}

// ---------------- Aggregate: out[n] = relu?( h[n]*dinv[n]^2 + b + sum_{s in N(n)} h[s]*dinv[s]*dinv[n] )
template<int F, bool RELU>
__global__ void k_aggregate(const float* __restrict__ h, const float* __restrict__ bias,
                            const float* __restrict__ dinv, const int* __restrict__ rowoff,
                            const int* __restrict__ col, float* __restrict__ out, int n) {
    constexpr int VEC = F / 64;
    int lane = threadIdx.x & 63;
    int wid  = threadIdx.x >> 6;
    int node = blockIdx.x * 4 + wid;
    if (node >= n) return;
    float di = dinv[node];
    float acc[VEC];
#pragma unroll
    for (int v = 0; v < VEC; ++v)
        acc[v] = h[(size_t)node * F + lane * VEC + v] * (di * di) + bias[lane * VEC + v];
    int s0 = rowoff[node], s1 = rowoff[node + 1];
    for (int e = s0; e < s1; ++e) {
        int s = col[e];
        float w = dinv[s] * di;
        if (VEC == 4) {
            float4 hv = *reinterpret_cast<const float4*>(&h[(size_t)s * F + lane * 4]);
            acc[0] += hv.x * w; acc[1] += hv.y * w;
            acc[2] += hv.z * w; acc[3] += hv.w * w;
        } else {
            acc[0] += h[(size_t)s * F + lane] * w;
        }
    }
#pragma unroll
    for (int v = 0; v < VEC; ++v) {
        float r = acc[v];
        if (RELU) r = fmaxf(r, 0.f);
        out[(size_t)node * F + lane * VEC + v] = r;
    }
}

// ---------------- Global mean pool (batch sorted) ----------------
__device__ __forceinline__ int lower_bound(const int* __restrict__ a, int n, int v) {
    int lo = 0, hi = n;
    while (lo < hi) {
        int mid = (lo + hi) >> 1;
        if (a[mid] < v) lo = mid + 1; else hi = mid;
    }
    return lo;
}

__global__ void k_pool(const float* __restrict__ h, const int* __restrict__ batch,
                       float* __restrict__ out, int n) {
    int g = blockIdx.x;     // graph id, 64 blocks
    int f = threadIdx.x;    // feature, 64 threads
    int start = lower_bound(batch, n, g);
    int end   = lower_bound(batch, n, g + 1);
    float s = 0.f;
    for (int i = start; i < end; ++i) s += h[(size_t)i * 64 + f];
    float denom = (float)max(end - start, 1);
    out[g * 64 + f] = s / denom;
}

// ---------------- Launch ----------------
extern "C" void kernel_launch(void* const* d_in, const int* in_sizes, int n_in,
                              void* d_out, int out_size, void* d_ws, size_t ws_size,
                              hipStream_t stream) {
    const float* x  = (const float*)d_in[0];
    const int* ei   = (const int*)d_in[1];
    const int* batch = (const int*)d_in[2];
    const float* W1 = (const float*)d_in[3]; const float* b1 = (const float*)d_in[4];
    const float* W2 = (const float*)d_in[5]; const float* b2 = (const float*)d_in[6];
    const float* W3 = (const float*)d_in[7]; const float* b3 = (const float*)d_in[8];
    float* out = (float*)d_out;

    const int n = in_sizes[0] / 128;
    const int E = in_sizes[1] / 2;
    const int* src = ei;
    const int* dst = ei + E;

    char* p = (char*)d_ws;
    auto carve = [&](size_t bytes) { char* q = p; p += (bytes + 255) & ~255ULL; return q; };
    float* A      = (float*)carve((size_t)n * 256 * 4);
    float* B      = (float*)carve((size_t)n * 256 * 4);
    float* C      = (float*)carve((size_t)n * 64 * 4);
    float* dinv   = (float*)carve((size_t)n * 4);
    int*   cnt    = (int*)carve((size_t)n * 4);
    int*   rowoff = (int*)carve((size_t)(n + 1) * 4);
    int*   cursor = (int*)carve((size_t)n * 4);
    int*   col    = (int*)carve((size_t)E * 4);

    hipMemsetAsync(cnt, 0, (size_t)n * 4, stream);
    k_count<<<(E + 255) / 256, 256, 0, stream>>>(dst, cnt, E);
    k_scan<<<1, 1024, 0, stream>>>(cnt, rowoff, cursor, dinv, n);
    k_fill<<<(E + 255) / 256, 256, 0, stream>>>(src, dst, cursor, col, E);

    dim3 blk(256);
    // Layer 1: h = x @ W1  (K=128, N=256)
    k_gemm<64, 64, 32><<<dim3(256 / 64, (n + 63) / 64), blk, 0, stream>>>(x, W1, A, n, 128, 256);
    k_aggregate<256, true><<<(n + 3) / 4, blk, 0, stream>>>(A, b1, dinv, rowoff, col, B, n);
    // Layer 2 (K=256, N=256)
    k_gemm<64, 64, 32><<<dim3(256 / 64, (n + 63) / 64), blk, 0, stream>>>(B, W2, A, n, 256, 256);
    k_aggregate<256, true><<<(n + 3) / 4, blk, 0, stream>>>(A, b2, dinv, rowoff, col, B, n);
    // Layer 3 (K=256, N=64)
    k_gemm<64, 64, 32><<<dim3(1, (n + 63) / 64), blk, 0, stream>>>(B, W3, C, n, 256, 64);
    k_aggregate<64, false><<<(n + 3) / 4, blk, 0, stream>>>(C, b3, dinv, rowoff, col, A, n);
    // Pool
    k_pool<<<64, 64, 0, stream>>>(A, batch, out, n);
}

// Round 5
// 303.111 us; speedup vs baseline: 1.2424x; 1.2424x over previous
//
#include <hip/hip_runtime.h>

// ---------------- CSR build ----------------

__global__ void k_count(const int* __restrict__ dst, int* __restrict__ cnt, int E) {
    int e = blockIdx.x * blockDim.x + threadIdx.x;
    if (e < E) atomicAdd(&cnt[dst[e]], 1);
}

// One block, 1024 threads: exclusive scan of cnt[0..n) -> rowoff[0..n], cursor copy,
// dinv = rsqrt(cnt+1).
#define SCAN_CHUNK 20
__global__ void k_scan(const int* __restrict__ cnt, int* __restrict__ rowoff,
                       int* __restrict__ cursor, float* __restrict__ dinv, int n) {
    __shared__ int psum[1024];
    int t = threadIdx.x;
    int base = t * SCAN_CHUNK;
    int vals[SCAN_CHUNK];
    int local = 0;
#pragma unroll
    for (int i = 0; i < SCAN_CHUNK; ++i) {
        int idx = base + i;
        vals[i] = (idx < n) ? cnt[idx] : 0;
        local += vals[i];
    }
    psum[t] = local;
    __syncthreads();
    // Hillis-Steele inclusive scan over 1024 partials
    for (int off = 1; off < 1024; off <<= 1) {
        int v = 0;
        if (t >= off) v = psum[t - off];
        __syncthreads();
        if (t >= off) psum[t] += v;
        __syncthreads();
    }
    int run = (t > 0) ? psum[t - 1] : 0;
#pragma unroll
    for (int i = 0; i < SCAN_CHUNK; ++i) {
        int idx = base + i;
        if (idx < n) {
            rowoff[idx] = run;
            cursor[idx] = run;
            dinv[idx]   = rsqrtf((float)(vals[i] + 1));
            run += vals[i];
        }
    }
    if (t == 1023) rowoff[n] = psum[1023];
}

__global__ void k_fill(const int* __restrict__ src, const int* __restrict__ dst,
                       int* __restrict__ cursor, int* __restrict__ col, int E) {
    int e = blockIdx.x * blockDim.x + threadIdx.x;
    if (e < E) {
        int pos = atomicAdd(&cursor[dst[e]], 1);
        col[pos] = src[e];
    }
}

// ---------------- GEMM (fp32, SIMT) ----------------
// C[M,N] = A[M,K] @ W[K,N]; BM=BN=64, BK=32, 256 threads, 4x4 micro-tile.
template<int BM, int BN, int BK>
__global__ void k_gemm(const float* __restrict__ A, const float* __restrict__ W,
                       float* __restrict__ C, int M, int K, int N) {
    __shared__ float As[BK][BM + 4];
    __shared__ float Bs[BK][BN + 4];
    const int tid = threadIdx.x;
    const int tx = tid & 15;   // col group
    const int ty = tid >> 4;   // row group
    const int bm = blockIdx.y * BM;
    const int bn = blockIdx.x * BN;

    float acc[4][4] = {};

    for (int k0 = 0; k0 < K; k0 += BK) {
        // A tile: BM x BK floats, float4 loads along K
#pragma unroll
        for (int i = 0; i < (BM * BK) / (256 * 4); ++i) {
            int idx = (tid + i * 256) * 4;
            int m = idx / BK, kk = idx % BK;
            int row = bm + m;
            float4 v = make_float4(0.f, 0.f, 0.f, 0.f);
            if (row < M) v = *reinterpret_cast<const float4*>(&A[(size_t)row * K + k0 + kk]);
            As[kk + 0][m] = v.x; As[kk + 1][m] = v.y;
            As[kk + 2][m] = v.z; As[kk + 3][m] = v.w;
        }
        // B tile: BK x BN floats
#pragma unroll
        for (int i = 0; i < (BK * BN) / (256 * 4); ++i) {
            int idx = (tid + i * 256) * 4;
            int kk = idx / BN, nn = idx % BN;
            float4 v = *reinterpret_cast<const float4*>(&W[(size_t)(k0 + kk) * N + bn + nn]);
            Bs[kk][nn + 0] = v.x; Bs[kk][nn + 1] = v.y;
            Bs[kk][nn + 2] = v.z; Bs[kk][nn + 3] = v.w;
        }
        __syncthreads();
#pragma unroll
        for (int kk = 0; kk < BK; ++kk) {
            float a[4], b[4];
#pragma unroll
            for (int i = 0; i < 4; ++i) a[i] = As[kk][ty * 4 + i];
#pragma unroll
            for (int j = 0; j < 4; ++j) b[j] = Bs[kk][tx * 4 + j];
#pragma unroll
            for (int i = 0; i < 4; ++i)
#pragma unroll
                for (int j = 0; j < 4; ++j) acc[i][j] += a[i] * b[j];
        }
        __syncthreads();
    }

#pragma unroll
    for (int i = 0; i < 4; ++i) {
        int row = bm + ty * 4 + i;
        if (row < M) {
            float4 v = make_float4(acc[i][0], acc[i][1], acc[i][2], acc[i][3]);
            *reinterpret_cast<float4*>(&C[(size_t)row * N + bn + tx * 4]) = v;
        }
    }
}

// ---------------- Aggregate: out[n] = relu?( h[n]*dinv[n]^2 + b + sum_{s in N(n)} h[s]*dinv[s]*dinv[n] )
template<int F, bool RELU>
__global__ void k_aggregate(const float* __restrict__ h, const float* __restrict__ bias,
                            const float* __restrict__ dinv, const int* __restrict__ rowoff,
                            const int* __restrict__ col, float* __restrict__ out, int n) {
    constexpr int VEC = F / 64;
    int lane = threadIdx.x & 63;
    int wid  = threadIdx.x >> 6;
    int node = blockIdx.x * 4 + wid;
    if (node >= n) return;
    float di = dinv[node];
    float acc[VEC];
#pragma unroll
    for (int v = 0; v < VEC; ++v)
        acc[v] = h[(size_t)node * F + lane * VEC + v] * (di * di) + bias[lane * VEC + v];
    int s0 = rowoff[node], s1 = rowoff[node + 1];
    for (int e = s0; e < s1; ++e) {
        int s = col[e];
        float w = dinv[s] * di;
        if (VEC == 4) {
            float4 hv = *reinterpret_cast<const float4*>(&h[(size_t)s * F + lane * 4]);
            acc[0] += hv.x * w; acc[1] += hv.y * w;
            acc[2] += hv.z * w; acc[3] += hv.w * w;
        } else {
            acc[0] += h[(size_t)s * F + lane] * w;
        }
    }
#pragma unroll
    for (int v = 0; v < VEC; ++v) {
        float r = acc[v];
        if (RELU) r = fmaxf(r, 0.f);
        out[(size_t)node * F + lane * VEC + v] = r;
    }
}

// ---------------- Global mean pool (batch sorted) ----------------
__device__ __forceinline__ int lower_bound(const int* __restrict__ a, int n, int v) {
    int lo = 0, hi = n;
    while (lo < hi) {
        int mid = (lo + hi) >> 1;
        if (a[mid] < v) lo = mid + 1; else hi = mid;
    }
    return lo;
}

// One block of 256 threads per graph: 16 float4-lanes cover the 64 features,
// 16 rows in flight, LDS tree-reduce. Deterministic order.
__global__ void k_pool(const float* __restrict__ h, const int* __restrict__ batch,
                       float* __restrict__ out, int n) {
    int g = blockIdx.x;          // graph id, 64 blocks
    int t = threadIdx.x;         // 256
    int fgrp = t & 15;           // float4 group: features fgrp*4 .. fgrp*4+3
    int rgrp = t >> 4;           // row group: 16 rows in flight
    int start = lower_bound(batch, n, g);
    int end   = lower_bound(batch, n, g + 1);
    float4 acc = make_float4(0.f, 0.f, 0.f, 0.f);
    for (int i = start + rgrp; i < end; i += 16) {
        float4 v = *reinterpret_cast<const float4*>(&h[(size_t)i * 64 + fgrp * 4]);
        acc.x += v.x; acc.y += v.y; acc.z += v.z; acc.w += v.w;
    }
    __shared__ float4 red[256];
    red[t] = acc;
    __syncthreads();
#pragma unroll
    for (int off = 8; off >= 1; off >>= 1) {
        if (rgrp < off) {
            float4 o = red[(rgrp + off) * 16 + fgrp];
            float4 m = red[t];
            m.x += o.x; m.y += o.y; m.z += o.z; m.w += o.w;
            red[t] = m;
        }
        __syncthreads();
    }
    if (rgrp == 0) {
        float denom = (float)max(end - start, 1);
        float4 m = red[fgrp];
        float4 r = make_float4(m.x / denom, m.y / denom, m.z / denom, m.w / denom);
        *reinterpret_cast<float4*>(&out[g * 64 + fgrp * 4]) = r;
    }
}

// ---------------- Launch ----------------
extern "C" void kernel_launch(void* const* d_in, const int* in_sizes, int n_in,
                              void* d_out, int out_size, void* d_ws, size_t ws_size,
                              hipStream_t stream) {
    const float* x  = (const float*)d_in[0];
    const int* ei   = (const int*)d_in[1];
    const int* batch = (const int*)d_in[2];
    const float* W1 = (const float*)d_in[3]; const float* b1 = (const float*)d_in[4];
    const float* W2 = (const float*)d_in[5]; const float* b2 = (const float*)d_in[6];
    const float* W3 = (const float*)d_in[7]; const float* b3 = (const float*)d_in[8];
    float* out = (float*)d_out;

    const int n = in_sizes[0] / 128;
    const int E = in_sizes[1] / 2;
    const int* src = ei;
    const int* dst = ei + E;

    char* p = (char*)d_ws;
    auto carve = [&](size_t bytes) { char* q = p; p += (bytes + 255) & ~255ULL; return q; };
    float* A      = (float*)carve((size_t)n * 256 * 4);
    float* B      = (float*)carve((size_t)n * 256 * 4);
    float* C      = (float*)carve((size_t)n * 64 * 4);
    float* dinv   = (float*)carve((size_t)n * 4);
    int*   cnt    = (int*)carve((size_t)n * 4);
    int*   rowoff = (int*)carve((size_t)(n + 1) * 4);
    int*   cursor = (int*)carve((size_t)n * 4);
    int*   col    = (int*)carve((size_t)E * 4);

    hipMemsetAsync(cnt, 0, (size_t)n * 4, stream);
    k_count<<<(E + 255) / 256, 256, 0, stream>>>(dst, cnt, E);
    k_scan<<<1, 1024, 0, stream>>>(cnt, rowoff, cursor, dinv, n);
    k_fill<<<(E + 255) / 256, 256, 0, stream>>>(src, dst, cursor, col, E);

    dim3 blk(256);
    // Layer 1: h = x @ W1  (K=128, N=256)
    k_gemm<64, 64, 32><<<dim3(256 / 64, (n + 63) / 64), blk, 0, stream>>>(x, W1, A, n, 128, 256);
    k_aggregate<256, true><<<(n + 3) / 4, blk, 0, stream>>>(A, b1, dinv, rowoff, col, B, n);
    // Layer 2 (K=256, N=256)
    k_gemm<64, 64, 32><<<dim3(256 / 64, (n + 63) / 64), blk, 0, stream>>>(B, W2, A, n, 256, 256);
    k_aggregate<256, true><<<(n + 3) / 4, blk, 0, stream>>>(A, b2, dinv, rowoff, col, B, n);
    // Layer 3 (K=256, N=64)
    k_gemm<64, 64, 32><<<dim3(1, (n + 63) / 64), blk, 0, stream>>>(B, W3, C, n, 256, 64);
    k_aggregate<64, false><<<(n + 3) / 4, blk, 0, stream>>>(C, b3, dinv, rowoff, col, A, n);
    // Pool: 256 threads/graph (16 float4-lanes x 16 rows in flight)
    k_pool<<<64, 256, 0, stream>>>(A, batch, out, n);
}

// Round 6
// 258.578 us; speedup vs baseline: 1.4564x; 1.1722x over previous
//
#include <hip/hip_runtime.h>

typedef __attribute__((ext_vector_type(8))) short short8v;   // 8 bf16 (4 VGPR)
typedef __attribute__((ext_vector_type(4))) float f32x4;     // MFMA acc

// ---------------- bf16 split helpers ----------------
__device__ __forceinline__ unsigned short bf16_rne(float v) {
    unsigned b = __float_as_uint(v);
    b += 0x7fffu + ((b >> 16) & 1u);
    return (unsigned short)(b >> 16);
}
// pack v into (hi bf16 << 16) | lo bf16, v ~= hi + lo with ~2^-16 rel error
__device__ __forceinline__ unsigned packsplit(float v) {
    unsigned short hs = bf16_rne(v);
    float r = v - __uint_as_float(((unsigned)hs) << 16);
    unsigned short ls = bf16_rne(r);
    return (((unsigned)hs) << 16) | (unsigned)ls;
}

// ---------------- CSR build ----------------
__global__ void k_count(const int* __restrict__ dst, int* __restrict__ cnt, int E) {
    int e = blockIdx.x * blockDim.x + threadIdx.x;
    if (e < E) atomicAdd(&cnt[dst[e]], 1);
}

#define SCAN_CHUNK 20
__global__ void k_scan(const int* __restrict__ cnt, int* __restrict__ rowoff,
                       int* __restrict__ cursor, float* __restrict__ dinv, int n) {
    __shared__ int psum[1024];
    int t = threadIdx.x;
    int base = t * SCAN_CHUNK;
    int vals[SCAN_CHUNK];
    int local = 0;
#pragma unroll
    for (int i = 0; i < SCAN_CHUNK; ++i) {
        int idx = base + i;
        vals[i] = (idx < n) ? cnt[idx] : 0;
        local += vals[i];
    }
    psum[t] = local;
    __syncthreads();
    for (int off = 1; off < 1024; off <<= 1) {
        int v = 0;
        if (t >= off) v = psum[t - off];
        __syncthreads();
        if (t >= off) psum[t] += v;
        __syncthreads();
    }
    int run = (t > 0) ? psum[t - 1] : 0;
#pragma unroll
    for (int i = 0; i < SCAN_CHUNK; ++i) {
        int idx = base + i;
        if (idx < n) {
            rowoff[idx] = run;
            cursor[idx] = run;
            dinv[idx]   = rsqrtf((float)(vals[i] + 1));
            run += vals[i];
        }
    }
    if (t == 1023) rowoff[n] = psum[1023];
}

__global__ void k_fill(const int* __restrict__ src, const int* __restrict__ dst,
                       int* __restrict__ cursor, int* __restrict__ col, int E) {
    int e = blockIdx.x * blockDim.x + threadIdx.x;
    if (e < E) {
        int pos = atomicAdd(&cursor[dst[e]], 1);
        col[pos] = src[e];
    }
}

// ---------------- W pre-split: W[K][N] f32 -> WT packed [N][K] uint ----------------
__global__ void k_split_w(const float* __restrict__ W, unsigned* __restrict__ WTp,
                          int K, int N) {
    int e = blockIdx.x * 256 + threadIdx.x;
    if (e >= K * N) return;
    int k = e / N, nn = e - k * N;
    WTp[(size_t)nn * K + k] = packsplit(W[e]);
}

// ---------------- MFMA split-bf16 GEMM ----------------
// C[M,N] = A[M,K] @ W[K,N] (+bias, relu). A packed [M][K], WT packed [N][K].
// 64x64 tile, BK=32, 256 thr = 4 waves each 32x32 (2x2 of 16x16x32 MFMA).
__device__ __forceinline__ void unpack8(const uint4 u0, const uint4 u1,
                                        short8v& hi, short8v& lo) {
    unsigned av[8] = {u0.x, u0.y, u0.z, u0.w, u1.x, u1.y, u1.z, u1.w};
#pragma unroll
    for (int i = 0; i < 8; ++i) {
        hi[i] = (short)(av[i] >> 16);
        lo[i] = (short)(av[i] & 0xffffu);
    }
}

template<bool HAS_BIAS, bool RELU, bool PACK_OUT>
__global__ __launch_bounds__(256)
void k_gemm_mfma(const unsigned* __restrict__ Ap, const unsigned* __restrict__ WTp,
                 const float* __restrict__ bias, void* __restrict__ Cout,
                 int M, int K, int N) {
    // row layout: [0..31] hi bf16 | [32..63] lo bf16 | [64..71] pad (144B stride)
    __shared__ __align__(16) unsigned short Ash[64][72];
    __shared__ __align__(16) unsigned short Bsh[64][72];
    const int tid = threadIdx.x;
    const int bm = blockIdx.y * 64, bn = blockIdx.x * 64;
    const int lane = tid & 63, w = tid >> 6;
    const int wm = (w >> 1) * 32, wn = (w & 1) * 32;
    const int m_st = tid >> 2, kq = tid & 3;   // staging: row, k-octet

    f32x4 acc[2][2];
#pragma unroll
    for (int i = 0; i < 2; ++i)
#pragma unroll
        for (int j = 0; j < 2; ++j) acc[i][j] = (f32x4){0.f, 0.f, 0.f, 0.f};

    for (int k0 = 0; k0 < K; k0 += 32) {
        // stage A tile (64 x 32 packed): thread -> 8 uints = 32B
        {
            int row = bm + m_st;
            uint4 u0 = {0,0,0,0}, u1 = {0,0,0,0};
            if (row < M) {
                const uint4* g = reinterpret_cast<const uint4*>(&Ap[(size_t)row * K + k0 + kq * 8]);
                u0 = g[0]; u1 = g[1];
            }
            short8v hi, lo;
            unpack8(u0, u1, hi, lo);
            *reinterpret_cast<short8v*>(&Ash[m_st][kq * 8])      = hi;
            *reinterpret_cast<short8v*>(&Ash[m_st][32 + kq * 8]) = lo;
        }
        // stage B tile from WT [N][K]: n-row = bm-style mapping
        {
            int nrow = bn + m_st;
            const uint4* g = reinterpret_cast<const uint4*>(&WTp[(size_t)nrow * K + k0 + kq * 8]);
            uint4 u0 = g[0], u1 = g[1];
            short8v hi, lo;
            unpack8(u0, u1, hi, lo);
            *reinterpret_cast<short8v*>(&Bsh[m_st][kq * 8])      = hi;
            *reinterpret_cast<short8v*>(&Bsh[m_st][32 + kq * 8]) = lo;
        }
        __syncthreads();

        short8v ah[2], al[2], bh[2], bl[2];
#pragma unroll
        for (int mi = 0; mi < 2; ++mi) {
            const unsigned short* p = &Ash[wm + mi * 16 + (lane & 15)][(lane >> 4) * 8];
            ah[mi] = *reinterpret_cast<const short8v*>(p);
            al[mi] = *reinterpret_cast<const short8v*>(p + 32);
        }
#pragma unroll
        for (int ni = 0; ni < 2; ++ni) {
            const unsigned short* p = &Bsh[wn + ni * 16 + (lane & 15)][(lane >> 4) * 8];
            bh[ni] = *reinterpret_cast<const short8v*>(p);
            bl[ni] = *reinterpret_cast<const short8v*>(p + 32);
        }
#pragma unroll
        for (int mi = 0; mi < 2; ++mi)
#pragma unroll
            for (int ni = 0; ni < 2; ++ni) {
                acc[mi][ni] = __builtin_amdgcn_mfma_f32_16x16x32_bf16(ah[mi], bh[ni], acc[mi][ni], 0, 0, 0);
                acc[mi][ni] = __builtin_amdgcn_mfma_f32_16x16x32_bf16(ah[mi], bl[ni], acc[mi][ni], 0, 0, 0);
                acc[mi][ni] = __builtin_amdgcn_mfma_f32_16x16x32_bf16(al[mi], bh[ni], acc[mi][ni], 0, 0, 0);
            }
        __syncthreads();
    }

    // epilogue: D row = (lane>>4)*4 + j, col = lane&15 (verified C/D mapping)
#pragma unroll
    for (int mi = 0; mi < 2; ++mi)
#pragma unroll
        for (int ni = 0; ni < 2; ++ni) {
            int colg = bn + wn + ni * 16 + (lane & 15);
            int rowb = bm + wm + mi * 16 + ((lane >> 4) << 2);
            float bv = 0.f;
            if constexpr (HAS_BIAS) bv = bias[colg];
#pragma unroll
            for (int j = 0; j < 4; ++j) {
                int row = rowb + j;
                if (row < M) {
                    float v = acc[mi][ni][j] + bv;
                    if constexpr (RELU) v = fmaxf(v, 0.f);
                    if constexpr (PACK_OUT)
                        ((unsigned*)Cout)[(size_t)row * N + colg] = packsplit(v);
                    else
                        ((float*)Cout)[(size_t)row * N + colg] = v;
                }
            }
        }
}

// ---------------- Aggregate: out = [relu]( h*dinv^2 [+ b] + sum_nbr h[s]*dinv[s]*dinv )
// input fp32; output fp32 or packed-split uint.
template<int F, bool HAS_BIAS, bool RELU, bool PACK>
__global__ void k_aggregate(const float* __restrict__ h, const float* __restrict__ bias,
                            const float* __restrict__ dinv, const int* __restrict__ rowoff,
                            const int* __restrict__ col, void* __restrict__ out, int n) {
    constexpr int VEC = F / 64;
    int lane = threadIdx.x & 63;
    int wid  = threadIdx.x >> 6;
    int node = blockIdx.x * 4 + wid;
    if (node >= n) return;
    float di = dinv[node];
    float acc[VEC];
    // self-loop (+bias)
#pragma unroll
    for (int v = 0; v < VEC; ++v) {
        acc[v] = h[(size_t)node * F + lane * VEC + v] * (di * di);
        if constexpr (HAS_BIAS) acc[v] += bias[lane * VEC + v];
    }
    int s0 = rowoff[node], s1 = rowoff[node + 1];
    for (int e = s0; e < s1; ++e) {
        int s = col[e];
        float wgt = dinv[s] * di;
        if constexpr (VEC == 4) {
            float4 hv = *reinterpret_cast<const float4*>(&h[(size_t)s * F + lane * 4]);
            acc[0] += hv.x * wgt; acc[1] += hv.y * wgt;
            acc[2] += hv.z * wgt; acc[3] += hv.w * wgt;
        } else if constexpr (VEC == 2) {
            float2 hv = *reinterpret_cast<const float2*>(&h[(size_t)s * F + lane * 2]);
            acc[0] += hv.x * wgt; acc[1] += hv.y * wgt;
        } else {
            acc[0] += h[(size_t)s * F + lane] * wgt;
        }
    }
#pragma unroll
    for (int v = 0; v < VEC; ++v)
        if constexpr (RELU) acc[v] = fmaxf(acc[v], 0.f);
    if constexpr (PACK) {
        unsigned pv[VEC];
#pragma unroll
        for (int v = 0; v < VEC; ++v) pv[v] = packsplit(acc[v]);
        unsigned* po = (unsigned*)out;
        if constexpr (VEC == 4)
            *reinterpret_cast<uint4*>(&po[(size_t)node * F + lane * 4]) =
                make_uint4(pv[0], pv[1], pv[2], pv[3]);
        else if constexpr (VEC == 2)
            *reinterpret_cast<uint2*>(&po[(size_t)node * F + lane * 2]) =
                make_uint2(pv[0], pv[1]);
        else
            po[(size_t)node * F + lane] = pv[0];
    } else {
        float* fo = (float*)out;
#pragma unroll
        for (int v = 0; v < VEC; ++v)
            fo[(size_t)node * F + lane * VEC + v] = acc[v];
    }
}

// ---------------- Global mean pool (batch sorted) ----------------
__device__ __forceinline__ int lower_bound(const int* __restrict__ a, int n, int v) {
    int lo = 0, hi = n;
    while (lo < hi) {
        int mid = (lo + hi) >> 1;
        if (a[mid] < v) lo = mid + 1; else hi = mid;
    }
    return lo;
}

__global__ void k_pool(const float* __restrict__ h, const int* __restrict__ batch,
                       float* __restrict__ out, int n) {
    int g = blockIdx.x;
    int t = threadIdx.x;          // 256
    int fgrp = t & 15;            // float4 group
    int rgrp = t >> 4;            // 16 rows in flight
    int start = lower_bound(batch, n, g);
    int end   = lower_bound(batch, n, g + 1);
    float4 acc = make_float4(0.f, 0.f, 0.f, 0.f);
    for (int i = start + rgrp; i < end; i += 16) {
        float4 v = *reinterpret_cast<const float4*>(&h[(size_t)i * 64 + fgrp * 4]);
        acc.x += v.x; acc.y += v.y; acc.z += v.z; acc.w += v.w;
    }
    __shared__ float4 red[256];
    red[t] = acc;
    __syncthreads();
#pragma unroll
    for (int off = 8; off >= 1; off >>= 1) {
        if (rgrp < off) {
            float4 o = red[(rgrp + off) * 16 + fgrp];
            float4 m = red[t];
            m.x += o.x; m.y += o.y; m.z += o.z; m.w += o.w;
            red[t] = m;
        }
        __syncthreads();
    }
    if (rgrp == 0) {
        float denom = (float)max(end - start, 1);
        float4 m = red[fgrp];
        *reinterpret_cast<float4*>(&out[g * 64 + fgrp * 4]) =
            make_float4(m.x / denom, m.y / denom, m.z / denom, m.w / denom);
    }
}

// ---------------- Launch ----------------
extern "C" void kernel_launch(void* const* d_in, const int* in_sizes, int n_in,
                              void* d_out, int out_size, void* d_ws, size_t ws_size,
                              hipStream_t stream) {
    const float* x  = (const float*)d_in[0];
    const int* ei   = (const int*)d_in[1];
    const int* batch = (const int*)d_in[2];
    const float* W1 = (const float*)d_in[3]; const float* b1 = (const float*)d_in[4];
    const float* W2 = (const float*)d_in[5]; const float* b2 = (const float*)d_in[6];
    const float* W3 = (const float*)d_in[7]; const float* b3 = (const float*)d_in[8];
    float* out = (float*)d_out;

    const int n = in_sizes[0] / 128;
    const int E = in_sizes[1] / 2;
    const int* src = ei;
    const int* dst = ei + E;

    char* p = (char*)d_ws;
    auto carve = [&](size_t bytes) { char* q = p; p += (bytes + 255) & ~255ULL; return q; };
    char* R1      = carve((size_t)n * 256 * 4);   // 20MB multi-use
    char* R2      = carve((size_t)n * 256 * 4);   // 20MB multi-use
    float* dinv   = (float*)carve((size_t)n * 4);
    int*   cnt    = (int*)carve((size_t)n * 4);
    int*   rowoff = (int*)carve((size_t)(n + 1) * 4);
    int*   cursor = (int*)carve((size_t)n * 4);
    int*   col    = (int*)carve((size_t)E * 4);
    unsigned* W1T = (unsigned*)carve((size_t)256 * 128 * 4);
    unsigned* W2T = (unsigned*)carve((size_t)256 * 256 * 4);
    unsigned* W3T = (unsigned*)carve((size_t)64 * 256 * 4);

    // region aliases (lifetimes verified disjoint)
    unsigned* P0 = (unsigned*)R1;                 // agg0 out, packed [n][128]
    float*    H1 = (float*)R2;                    // gemm1 out, f32 [n][256]
    unsigned* P1 = (unsigned*)R1;                 // agg1 out, packed [n][256] (P0 dead)
    unsigned* P2 = (unsigned*)R2;                 // gemm2 out, packed [n][256] (H1 dead)
    float*    T3 = (float*)R1;                    // gemm3 out, f32 [n][64] (P1 dead)
    float*    H3 = (float*)R1 + (size_t)n * 64;   // agg3 out, f32 [n][64]

    hipMemsetAsync(cnt, 0, (size_t)n * 4, stream);
    k_count<<<(E + 255) / 256, 256, 0, stream>>>(dst, cnt, E);
    k_scan<<<1, 1024, 0, stream>>>(cnt, rowoff, cursor, dinv, n);
    k_fill<<<(E + 255) / 256, 256, 0, stream>>>(src, dst, cursor, col, E);
    k_split_w<<<(128 * 256 + 255) / 256, 256, 0, stream>>>(W1, W1T, 128, 256);
    k_split_w<<<(256 * 256 + 255) / 256, 256, 0, stream>>>(W2, W2T, 256, 256);
    k_split_w<<<(256 * 64 + 255) / 256, 256, 0, stream>>>(W3, W3T, 256, 64);

    const int mblocks = (n + 63) / 64;
    // layer 1: agg0 = N(x) [packed]; h1 = relu(agg0 @ W1 + b1) [f32]
    k_aggregate<128, false, false, true><<<(n + 3) / 4, 256, 0, stream>>>(
        x, nullptr, dinv, rowoff, col, P0, n);
    k_gemm_mfma<true, true, false><<<dim3(4, mblocks), 256, 0, stream>>>(
        P0, W1T, b1, H1, n, 128, 256);
    // layer 2: agg1 = N(h1) [packed]; h2 = relu(agg1 @ W2 + b2) [packed]
    k_aggregate<256, false, false, true><<<(n + 3) / 4, 256, 0, stream>>>(
        H1, nullptr, dinv, rowoff, col, P1, n);
    k_gemm_mfma<true, true, true><<<dim3(4, mblocks), 256, 0, stream>>>(
        P1, W2T, b2, P2, n, 256, 256);
    // layer 3: t = h2 @ W3 [f32]; h3 = N(t) + b3 [f32]
    k_gemm_mfma<false, false, false><<<dim3(1, mblocks), 256, 0, stream>>>(
        P2, W3T, nullptr, T3, n, 256, 64);
    k_aggregate<64, true, false, false><<<(n + 3) / 4, 256, 0, stream>>>(
        T3, b3, dinv, rowoff, col, H3, n);
    // pool
    k_pool<<<64, 256, 0, stream>>>(H3, batch, out, n);
}

// Round 7
// 224.972 us; speedup vs baseline: 1.6739x; 1.1494x over previous
//
#include <hip/hip_runtime.h>

typedef __attribute__((ext_vector_type(8))) short short8v;   // 8 bf16 (4 VGPR)
typedef __attribute__((ext_vector_type(4))) float f32x4;     // MFMA acc

// ---------------- bf16 split helpers ----------------
__device__ __forceinline__ unsigned short bf16_rne(float v) {
    unsigned b = __float_as_uint(v);
    b += 0x7fffu + ((b >> 16) & 1u);
    return (unsigned short)(b >> 16);
}
// pack v into (hi bf16 << 16) | lo bf16, v ~= hi + lo with ~2^-16 rel error
__device__ __forceinline__ unsigned packsplit(float v) {
    unsigned short hs = bf16_rne(v);
    float r = v - __uint_as_float(((unsigned)hs) << 16);
    unsigned short ls = bf16_rne(r);
    return (((unsigned)hs) << 16) | (unsigned)ls;
}

// ---------------- CSR build ----------------
__global__ void k_count(const int* __restrict__ dst, int* __restrict__ cnt, int E) {
    int e = blockIdx.x * blockDim.x + threadIdx.x;
    if (e < E) atomicAdd(&cnt[dst[e]], 1);
}

#define SCAN_CHUNK 20
__global__ void k_scan(const int* __restrict__ cnt, int* __restrict__ rowoff,
                       int* __restrict__ cursor, float* __restrict__ dinv, int n) {
    __shared__ int psum[1024];
    int t = threadIdx.x;
    int base = t * SCAN_CHUNK;
    int vals[SCAN_CHUNK];
    int local = 0;
#pragma unroll
    for (int i = 0; i < SCAN_CHUNK; ++i) {
        int idx = base + i;
        vals[i] = (idx < n) ? cnt[idx] : 0;
        local += vals[i];
    }
    psum[t] = local;
    __syncthreads();
    for (int off = 1; off < 1024; off <<= 1) {
        int v = 0;
        if (t >= off) v = psum[t - off];
        __syncthreads();
        if (t >= off) psum[t] += v;
        __syncthreads();
    }
    int run = (t > 0) ? psum[t - 1] : 0;
#pragma unroll
    for (int i = 0; i < SCAN_CHUNK; ++i) {
        int idx = base + i;
        if (idx < n) {
            rowoff[idx] = run;
            cursor[idx] = run;
            dinv[idx]   = rsqrtf((float)(vals[i] + 1));
            run += vals[i];
        }
    }
    if (t == 1023) rowoff[n] = psum[1023];
}

__global__ void k_fill(const int* __restrict__ src, const int* __restrict__ dst,
                       int* __restrict__ cursor, int* __restrict__ col, int E) {
    int e = blockIdx.x * blockDim.x + threadIdx.x;
    if (e < E) {
        int pos = atomicAdd(&cursor[dst[e]], 1);
        col[pos] = src[e];
    }
}

// ---------------- W pre-split (all 3 weights in one launch) ----------------
__global__ void k_split_w_all(const float* __restrict__ W1, const float* __restrict__ W2,
                              const float* __restrict__ W3, unsigned* __restrict__ W1T,
                              unsigned* __restrict__ W2T, unsigned* __restrict__ W3T) {
    int e = blockIdx.x * 256 + threadIdx.x;
    // W1: 128x256 -> [256][128]; W2: 256x256; W3: 256x64 -> [64][256]
    if (e < 128 * 256) {
        int k = e >> 8, nn = e & 255;
        W1T[(size_t)nn * 128 + k] = packsplit(W1[e]);
    } else if (e < 128 * 256 + 256 * 256) {
        int e2 = e - 128 * 256;
        int k = e2 >> 8, nn = e2 & 255;
        W2T[(size_t)nn * 256 + k] = packsplit(W2[e2]);
    } else if (e < 128 * 256 + 256 * 256 + 256 * 64) {
        int e3 = e - 128 * 256 - 256 * 256;
        int k = e3 >> 6, nn = e3 & 63;
        W3T[(size_t)nn * 256 + k] = packsplit(W3[e3]);
    }
}

// ---------------- x prescale: x'[r][c] = x[r][c] * dinv[r] ----------------
__global__ void k_prescale(const float* __restrict__ x, const float* __restrict__ dinv,
                           float* __restrict__ xp, int total4 /* n*128/4 */) {
    int i = blockIdx.x * 256 + threadIdx.x;
    if (i >= total4) return;
    float4 v = reinterpret_cast<const float4*>(x)[i];
    float d = dinv[i >> 5];   // 32 float4 per 128-wide row
    v.x *= d; v.y *= d; v.z *= d; v.w *= d;
    reinterpret_cast<float4*>(xp)[i] = v;
}

// ---------------- MFMA split-bf16 GEMM ----------------
// C[M,N] = A[M,K] @ W[K,N] (+bias, relu, *dinv[row], pack). A packed [M][K], WT packed [N][K].
// 64x64 tile, BK=32, 256 thr = 4 waves each 32x32 (2x2 of 16x16x32 MFMA).
__device__ __forceinline__ void unpack8(const uint4 u0, const uint4 u1,
                                        short8v& hi, short8v& lo) {
    unsigned av[8] = {u0.x, u0.y, u0.z, u0.w, u1.x, u1.y, u1.z, u1.w};
#pragma unroll
    for (int i = 0; i < 8; ++i) {
        hi[i] = (short)(av[i] >> 16);
        lo[i] = (short)(av[i] & 0xffffu);
    }
}

template<bool HAS_BIAS, bool RELU, bool SCALE, bool PACK_OUT>
__global__ __launch_bounds__(256)
void k_gemm_mfma(const unsigned* __restrict__ Ap, const unsigned* __restrict__ WTp,
                 const float* __restrict__ bias, const float* __restrict__ dscale,
                 void* __restrict__ Cout, int M, int K, int N) {
    // row layout: [0..31] hi bf16 | [32..63] lo bf16 | pad to 144B stride
    __shared__ __align__(16) unsigned short Ash[64][72];
    __shared__ __align__(16) unsigned short Bsh[64][72];
    const int tid = threadIdx.x;
    const int bm = blockIdx.y * 64, bn = blockIdx.x * 64;
    const int lane = tid & 63, w = tid >> 6;
    const int wm = (w >> 1) * 32, wn = (w & 1) * 32;
    const int m_st = tid >> 2, kq = tid & 3;   // staging: row, k-octet

    f32x4 acc[2][2];
#pragma unroll
    for (int i = 0; i < 2; ++i)
#pragma unroll
        for (int j = 0; j < 2; ++j) acc[i][j] = (f32x4){0.f, 0.f, 0.f, 0.f};

    for (int k0 = 0; k0 < K; k0 += 32) {
        {
            int row = bm + m_st;
            uint4 u0 = {0,0,0,0}, u1 = {0,0,0,0};
            if (row < M) {
                const uint4* g = reinterpret_cast<const uint4*>(&Ap[(size_t)row * K + k0 + kq * 8]);
                u0 = g[0]; u1 = g[1];
            }
            short8v hi, lo;
            unpack8(u0, u1, hi, lo);
            *reinterpret_cast<short8v*>(&Ash[m_st][kq * 8])      = hi;
            *reinterpret_cast<short8v*>(&Ash[m_st][32 + kq * 8]) = lo;
        }
        {
            int nrow = bn + m_st;
            const uint4* g = reinterpret_cast<const uint4*>(&WTp[(size_t)nrow * K + k0 + kq * 8]);
            uint4 u0 = g[0], u1 = g[1];
            short8v hi, lo;
            unpack8(u0, u1, hi, lo);
            *reinterpret_cast<short8v*>(&Bsh[m_st][kq * 8])      = hi;
            *reinterpret_cast<short8v*>(&Bsh[m_st][32 + kq * 8]) = lo;
        }
        __syncthreads();

        short8v ah[2], al[2], bh[2], bl[2];
#pragma unroll
        for (int mi = 0; mi < 2; ++mi) {
            const unsigned short* p = &Ash[wm + mi * 16 + (lane & 15)][(lane >> 4) * 8];
            ah[mi] = *reinterpret_cast<const short8v*>(p);
            al[mi] = *reinterpret_cast<const short8v*>(p + 32);
        }
#pragma unroll
        for (int ni = 0; ni < 2; ++ni) {
            const unsigned short* p = &Bsh[wn + ni * 16 + (lane & 15)][(lane >> 4) * 8];
            bh[ni] = *reinterpret_cast<const short8v*>(p);
            bl[ni] = *reinterpret_cast<const short8v*>(p + 32);
        }
#pragma unroll
        for (int mi = 0; mi < 2; ++mi)
#pragma unroll
            for (int ni = 0; ni < 2; ++ni) {
                acc[mi][ni] = __builtin_amdgcn_mfma_f32_16x16x32_bf16(ah[mi], bh[ni], acc[mi][ni], 0, 0, 0);
                acc[mi][ni] = __builtin_amdgcn_mfma_f32_16x16x32_bf16(ah[mi], bl[ni], acc[mi][ni], 0, 0, 0);
                acc[mi][ni] = __builtin_amdgcn_mfma_f32_16x16x32_bf16(al[mi], bh[ni], acc[mi][ni], 0, 0, 0);
            }
        __syncthreads();
    }

    // epilogue: D row = (lane>>4)*4 + j, col = lane&15 (verified C/D mapping)
#pragma unroll
    for (int mi = 0; mi < 2; ++mi)
#pragma unroll
        for (int ni = 0; ni < 2; ++ni) {
            int colg = bn + wn + ni * 16 + (lane & 15);
            int rowb = bm + wm + mi * 16 + ((lane >> 4) << 2);
            float bv = 0.f;
            if constexpr (HAS_BIAS) bv = bias[colg];
#pragma unroll
            for (int j = 0; j < 4; ++j) {
                int row = rowb + j;
                if (row < M) {
                    float v = acc[mi][ni][j] + bv;
                    if constexpr (RELU) v = fmaxf(v, 0.f);
                    if constexpr (SCALE) v *= dscale[row];
                    if constexpr (PACK_OUT)
                        ((unsigned*)Cout)[(size_t)row * N + colg] = packsplit(v);
                    else
                        ((float*)Cout)[(size_t)row * N + colg] = v;
                }
            }
        }
}

// ---------------- Aggregate (prescaled input h' = dinv .* h):
// out_i = dinv_i * ( h'_i + sum_{s in N(i)} h'_s )  [+ bias]
// 4-deep unrolled gather: 4 independent accumulator banks for MLP.
template<int F, bool HAS_BIAS, bool PACK>
__global__ void k_aggregate(const float* __restrict__ h, const float* __restrict__ bias,
                            const float* __restrict__ dinv, const int* __restrict__ rowoff,
                            const int* __restrict__ col, void* __restrict__ out, int n) {
    constexpr int VEC = F / 64;
    int lane = threadIdx.x & 63;
    int wid  = threadIdx.x >> 6;
    int node = blockIdx.x * 4 + wid;
    if (node >= n) return;
    float di = dinv[node];
    float acc[4][VEC];
    // bank 0 starts with the self row
#pragma unroll
    for (int v = 0; v < VEC; ++v) acc[0][v] = h[(size_t)node * F + lane * VEC + v];
#pragma unroll
    for (int b = 1; b < 4; ++b)
#pragma unroll
        for (int v = 0; v < VEC; ++v) acc[b][v] = 0.f;

    int e = rowoff[node], s1 = rowoff[node + 1];
    for (; e + 3 < s1; e += 4) {
        int s_0 = col[e], s_1 = col[e + 1], s_2 = col[e + 2], s_3 = col[e + 3];
        const float* p0 = &h[(size_t)s_0 * F + lane * VEC];
        const float* p1 = &h[(size_t)s_1 * F + lane * VEC];
        const float* p2 = &h[(size_t)s_2 * F + lane * VEC];
        const float* p3 = &h[(size_t)s_3 * F + lane * VEC];
        if constexpr (VEC == 4) {
            float4 v0 = *reinterpret_cast<const float4*>(p0);
            float4 v1 = *reinterpret_cast<const float4*>(p1);
            float4 v2 = *reinterpret_cast<const float4*>(p2);
            float4 v3 = *reinterpret_cast<const float4*>(p3);
            acc[0][0] += v0.x; acc[0][1] += v0.y; acc[0][2] += v0.z; acc[0][3] += v0.w;
            acc[1][0] += v1.x; acc[1][1] += v1.y; acc[1][2] += v1.z; acc[1][3] += v1.w;
            acc[2][0] += v2.x; acc[2][1] += v2.y; acc[2][2] += v2.z; acc[2][3] += v2.w;
            acc[3][0] += v3.x; acc[3][1] += v3.y; acc[3][2] += v3.z; acc[3][3] += v3.w;
        } else if constexpr (VEC == 2) {
            float2 v0 = *reinterpret_cast<const float2*>(p0);
            float2 v1 = *reinterpret_cast<const float2*>(p1);
            float2 v2 = *reinterpret_cast<const float2*>(p2);
            float2 v3 = *reinterpret_cast<const float2*>(p3);
            acc[0][0] += v0.x; acc[0][1] += v0.y;
            acc[1][0] += v1.x; acc[1][1] += v1.y;
            acc[2][0] += v2.x; acc[2][1] += v2.y;
            acc[3][0] += v3.x; acc[3][1] += v3.y;
        } else {
            acc[0][0] += *p0; acc[1][0] += *p1; acc[2][0] += *p2; acc[3][0] += *p3;
        }
    }
    for (; e < s1; ++e) {
        int s = col[e];
        const float* p = &h[(size_t)s * F + lane * VEC];
#pragma unroll
        for (int v = 0; v < VEC; ++v) acc[0][v] += p[v];
    }

    float r[VEC];
#pragma unroll
    for (int v = 0; v < VEC; ++v)
        r[v] = ((acc[0][v] + acc[1][v]) + (acc[2][v] + acc[3][v])) * di;
    if constexpr (HAS_BIAS) {
#pragma unroll
        for (int v = 0; v < VEC; ++v) r[v] += bias[lane * VEC + v];
    }

    if constexpr (PACK) {
        unsigned pv[VEC];
#pragma unroll
        for (int v = 0; v < VEC; ++v) pv[v] = packsplit(r[v]);
        unsigned* po = (unsigned*)out;
        if constexpr (VEC == 4)
            *reinterpret_cast<uint4*>(&po[(size_t)node * F + lane * 4]) =
                make_uint4(pv[0], pv[1], pv[2], pv[3]);
        else if constexpr (VEC == 2)
            *reinterpret_cast<uint2*>(&po[(size_t)node * F + lane * 2]) =
                make_uint2(pv[0], pv[1]);
        else
            po[(size_t)node * F + lane] = pv[0];
    } else {
        float* fo = (float*)out;
#pragma unroll
        for (int v = 0; v < VEC; ++v)
            fo[(size_t)node * F + lane * VEC + v] = r[v];
    }
}

// ---------------- Global mean pool (batch sorted) ----------------
__device__ __forceinline__ int lower_bound(const int* __restrict__ a, int n, int v) {
    int lo = 0, hi = n;
    while (lo < hi) {
        int mid = (lo + hi) >> 1;
        if (a[mid] < v) lo = mid + 1; else hi = mid;
    }
    return lo;
}

__global__ void k_pool(const float* __restrict__ h, const int* __restrict__ batch,
                       float* __restrict__ out, int n) {
    int g = blockIdx.x;
    int t = threadIdx.x;          // 256
    int fgrp = t & 15;            // float4 group
    int rgrp = t >> 4;            // 16 rows in flight
    int start = lower_bound(batch, n, g);
    int end   = lower_bound(batch, n, g + 1);
    float4 acc = make_float4(0.f, 0.f, 0.f, 0.f);
    for (int i = start + rgrp; i < end; i += 16) {
        float4 v = *reinterpret_cast<const float4*>(&h[(size_t)i * 64 + fgrp * 4]);
        acc.x += v.x; acc.y += v.y; acc.z += v.z; acc.w += v.w;
    }
    __shared__ float4 red[256];
    red[t] = acc;
    __syncthreads();
#pragma unroll
    for (int off = 8; off >= 1; off >>= 1) {
        if (rgrp < off) {
            float4 o = red[(rgrp + off) * 16 + fgrp];
            float4 m = red[t];
            m.x += o.x; m.y += o.y; m.z += o.z; m.w += o.w;
            red[t] = m;
        }
        __syncthreads();
    }
    if (rgrp == 0) {
        float denom = (float)max(end - start, 1);
        float4 m = red[fgrp];
        *reinterpret_cast<float4*>(&out[g * 64 + fgrp * 4]) =
            make_float4(m.x / denom, m.y / denom, m.z / denom, m.w / denom);
    }
}

// ---------------- Launch ----------------
extern "C" void kernel_launch(void* const* d_in, const int* in_sizes, int n_in,
                              void* d_out, int out_size, void* d_ws, size_t ws_size,
                              hipStream_t stream) {
    const float* x  = (const float*)d_in[0];
    const int* ei   = (const int*)d_in[1];
    const int* batch = (const int*)d_in[2];
    const float* W1 = (const float*)d_in[3]; const float* b1 = (const float*)d_in[4];
    const float* W2 = (const float*)d_in[5]; const float* b2 = (const float*)d_in[6];
    const float* W3 = (const float*)d_in[7]; const float* b3 = (const float*)d_in[8];
    float* out = (float*)d_out;

    const int n = in_sizes[0] / 128;
    const int E = in_sizes[1] / 2;
    const int* src = ei;
    const int* dst = ei + E;

    char* p = (char*)d_ws;
    auto carve = [&](size_t bytes) { char* q = p; p += (bytes + 255) & ~255ULL; return q; };
    char* R1      = carve((size_t)n * 256 * 4);   // 20MB multi-use
    char* R2      = carve((size_t)n * 256 * 4);   // 20MB multi-use
    float* dinv   = (float*)carve((size_t)n * 4);
    int*   cnt    = (int*)carve((size_t)n * 4);
    int*   rowoff = (int*)carve((size_t)(n + 1) * 4);
    int*   cursor = (int*)carve((size_t)n * 4);
    int*   col    = (int*)carve((size_t)E * 4);
    unsigned* W1T = (unsigned*)carve((size_t)256 * 128 * 4);
    unsigned* W2T = (unsigned*)carve((size_t)256 * 256 * 4);
    unsigned* W3T = (unsigned*)carve((size_t)64 * 256 * 4);

    // region aliases (lifetimes disjoint):
    float*    XP = (float*)R2;                    // x' = dinv.*x, f32 [n][128]
    unsigned* P0 = (unsigned*)R1;                 // agg0 out, packed [n][128]
    float*    H1 = (float*)R2;                    // gemm1 out (scaled), f32 [n][256] (XP dead)
    unsigned* P1 = (unsigned*)R1;                 // agg1 out, packed [n][256] (P0 dead)
    unsigned* P2 = (unsigned*)R2;                 // gemm2 out, packed [n][256] (H1 dead)
    float*    T3 = (float*)R1;                    // gemm3 out (scaled), f32 [n][64] (P1 dead)
    float*    H3 = (float*)R1 + (size_t)n * 64;   // agg3 out, f32 [n][64]

    hipMemsetAsync(cnt, 0, (size_t)n * 4, stream);
    k_count<<<(E + 255) / 256, 256, 0, stream>>>(dst, cnt, E);
    k_scan<<<1, 1024, 0, stream>>>(cnt, rowoff, cursor, dinv, n);
    k_fill<<<(E + 255) / 256, 256, 0, stream>>>(src, dst, cursor, col, E);
    k_split_w_all<<<(128*256 + 256*256 + 256*64 + 255) / 256, 256, 0, stream>>>(
        W1, W2, W3, W1T, W2T, W3T);

    const int mblocks = (n + 63) / 64;
    // layer 1: x'=dinv.*x; agg0 = dinv.*(gather-sum x') [packed]; h1' = relu(agg0@W1+b1).*dinv [f32]
    k_prescale<<<((n * 128 / 4) + 255) / 256, 256, 0, stream>>>(x, dinv, XP, n * 128 / 4);
    k_aggregate<128, false, true><<<(n + 3) / 4, 256, 0, stream>>>(
        XP, nullptr, dinv, rowoff, col, P0, n);
    k_gemm_mfma<true, true, true, false><<<dim3(4, mblocks), 256, 0, stream>>>(
        P0, W1T, b1, dinv, H1, n, 128, 256);
    // layer 2: agg1 = dinv.*(gather-sum h1') [packed]; h2 = relu(agg1@W2+b2) [packed, unscaled]
    k_aggregate<256, false, true><<<(n + 3) / 4, 256, 0, stream>>>(
        H1, nullptr, dinv, rowoff, col, P1, n);
    k_gemm_mfma<true, true, false, true><<<dim3(4, mblocks), 256, 0, stream>>>(
        P1, W2T, b2, nullptr, P2, n, 256, 256);
    // layer 3: t' = (h2@W3).*dinv [f32]; h3 = dinv.*(gather-sum t') + b3 [f32]
    k_gemm_mfma<false, false, true, false><<<dim3(1, mblocks), 256, 0, stream>>>(
        P2, W3T, nullptr, dinv, T3, n, 256, 64);
    k_aggregate<64, true, false><<<(n + 3) / 4, 256, 0, stream>>>(
        T3, b3, dinv, rowoff, col, H3, n);
    // pool
    k_pool<<<64, 256, 0, stream>>>(H3, batch, out, n);
}

// Round 8
// 197.472 us; speedup vs baseline: 1.9071x; 1.1393x over previous
//
#include <hip/hip_runtime.h>
#include <hip/hip_fp16.h>

typedef __attribute__((ext_vector_type(8))) short short8v;   // 8 bf16 (4 VGPR)
typedef __attribute__((ext_vector_type(4))) float f32x4;     // MFMA acc

// ---------------- bf16 split helpers ----------------
__device__ __forceinline__ unsigned short bf16_rne(float v) {
    unsigned b = __float_as_uint(v);
    b += 0x7fffu + ((b >> 16) & 1u);
    return (unsigned short)(b >> 16);
}
// pack v into (hi bf16 << 16) | lo bf16, v ~= hi + lo with ~2^-16 rel error
__device__ __forceinline__ unsigned packsplit(float v) {
    unsigned short hs = bf16_rne(v);
    float r = v - __uint_as_float(((unsigned)hs) << 16);
    unsigned short ls = bf16_rne(r);
    return (((unsigned)hs) << 16) | (unsigned)ls;
}
__device__ __forceinline__ float h2f_lo(unsigned u) {
    return __half2float(__ushort_as_half((unsigned short)(u & 0xffffu)));
}
__device__ __forceinline__ float h2f_hi(unsigned u) {
    return __half2float(__ushort_as_half((unsigned short)(u >> 16)));
}
__device__ __forceinline__ unsigned f2h_pack(float a, float b) {
    return (unsigned)__half_as_ushort(__float2half(a)) |
           ((unsigned)__half_as_ushort(__float2half(b)) << 16);
}

// ---------------- CSR build ----------------
__global__ void k_count(const int* __restrict__ dst, int* __restrict__ cnt, int E) {
    int e = blockIdx.x * blockDim.x + threadIdx.x;
    if (e < E) atomicAdd(&cnt[dst[e]], 1);
}

#define SCAN_CHUNK 20
__global__ void k_scan(const int* __restrict__ cnt, int* __restrict__ rowoff,
                       int* __restrict__ cursor, float* __restrict__ dinv, int n) {
    __shared__ int psum[1024];
    int t = threadIdx.x;
    int base = t * SCAN_CHUNK;
    int vals[SCAN_CHUNK];
    int local = 0;
#pragma unroll
    for (int i = 0; i < SCAN_CHUNK; ++i) {
        int idx = base + i;
        vals[i] = (idx < n) ? cnt[idx] : 0;
        local += vals[i];
    }
    psum[t] = local;
    __syncthreads();
    for (int off = 1; off < 1024; off <<= 1) {
        int v = 0;
        if (t >= off) v = psum[t - off];
        __syncthreads();
        if (t >= off) psum[t] += v;
        __syncthreads();
    }
    int run = (t > 0) ? psum[t - 1] : 0;
#pragma unroll
    for (int i = 0; i < SCAN_CHUNK; ++i) {
        int idx = base + i;
        if (idx < n) {
            rowoff[idx] = run;
            cursor[idx] = run;
            dinv[idx]   = rsqrtf((float)(vals[i] + 1));
            run += vals[i];
        }
    }
    if (t == 1023) rowoff[n] = psum[1023];
}

__global__ void k_fill(const int* __restrict__ src, const int* __restrict__ dst,
                       int* __restrict__ cursor, int* __restrict__ col, int E) {
    int e = blockIdx.x * blockDim.x + threadIdx.x;
    if (e < E) {
        int pos = atomicAdd(&cursor[dst[e]], 1);
        col[pos] = src[e];
    }
}

// ---------------- W pre-split (all 3 weights in one launch) ----------------
__global__ void k_split_w_all(const float* __restrict__ W1, const float* __restrict__ W2,
                              const float* __restrict__ W3, unsigned* __restrict__ W1T,
                              unsigned* __restrict__ W2T, unsigned* __restrict__ W3T) {
    int e = blockIdx.x * 256 + threadIdx.x;
    if (e < 128 * 256) {
        int k = e >> 8, nn = e & 255;
        W1T[(size_t)nn * 128 + k] = packsplit(W1[e]);
    } else if (e < 128 * 256 + 256 * 256) {
        int e2 = e - 128 * 256;
        int k = e2 >> 8, nn = e2 & 255;
        W2T[(size_t)nn * 256 + k] = packsplit(W2[e2]);
    } else if (e < 128 * 256 + 256 * 256 + 256 * 64) {
        int e3 = e - 128 * 256 - 256 * 256;
        int k = e3 >> 6, nn = e3 & 63;
        W3T[(size_t)nn * 256 + k] = packsplit(W3[e3]);
    }
}

// ---------------- x prescale: xp[r][c] = fp16( x[r][c] * dinv[r] ) ----------------
__global__ void k_prescale(const float* __restrict__ x, const float* __restrict__ dinv,
                           __half* __restrict__ xp, int total4 /* n*128/4 */) {
    int i = blockIdx.x * 256 + threadIdx.x;
    if (i >= total4) return;
    float4 v = reinterpret_cast<const float4*>(x)[i];
    float d = dinv[i >> 5];   // 32 float4 per 128-wide row
    reinterpret_cast<uint2*>(xp)[i] =
        make_uint2(f2h_pack(v.x * d, v.y * d), f2h_pack(v.z * d, v.w * d));
}

// ---------------- MFMA split-bf16 GEMM ----------------
// C[M,N] = A[M,K] @ W[K,N] (+bias, relu, *dinv[row]). A packed [M][K], WT packed [N][K].
// 64x64 tile, BK=32, 256 thr = 4 waves each 32x32 (2x2 of 16x16x32 MFMA).
// Output: packed-split u32 | fp16 | f32.
__device__ __forceinline__ void unpack8(const uint4 u0, const uint4 u1,
                                        short8v& hi, short8v& lo) {
    unsigned av[8] = {u0.x, u0.y, u0.z, u0.w, u1.x, u1.y, u1.z, u1.w};
#pragma unroll
    for (int i = 0; i < 8; ++i) {
        hi[i] = (short)(av[i] >> 16);
        lo[i] = (short)(av[i] & 0xffffu);
    }
}

template<bool HAS_BIAS, bool RELU, bool SCALE, bool PACK_OUT, bool F16_OUT>
__global__ __launch_bounds__(256)
void k_gemm_mfma(const unsigned* __restrict__ Ap, const unsigned* __restrict__ WTp,
                 const float* __restrict__ bias, const float* __restrict__ dscale,
                 void* __restrict__ Cout, int M, int K, int N) {
    __shared__ __align__(16) unsigned short Ash[64][72];
    __shared__ __align__(16) unsigned short Bsh[64][72];
    const int tid = threadIdx.x;
    const int bm = blockIdx.y * 64, bn = blockIdx.x * 64;
    const int lane = tid & 63, w = tid >> 6;
    const int wm = (w >> 1) * 32, wn = (w & 1) * 32;
    const int m_st = tid >> 2, kq = tid & 3;   // staging: row, k-octet

    f32x4 acc[2][2];
#pragma unroll
    for (int i = 0; i < 2; ++i)
#pragma unroll
        for (int j = 0; j < 2; ++j) acc[i][j] = (f32x4){0.f, 0.f, 0.f, 0.f};

    for (int k0 = 0; k0 < K; k0 += 32) {
        {
            int row = bm + m_st;
            uint4 u0 = {0,0,0,0}, u1 = {0,0,0,0};
            if (row < M) {
                const uint4* g = reinterpret_cast<const uint4*>(&Ap[(size_t)row * K + k0 + kq * 8]);
                u0 = g[0]; u1 = g[1];
            }
            short8v hi, lo;
            unpack8(u0, u1, hi, lo);
            *reinterpret_cast<short8v*>(&Ash[m_st][kq * 8])      = hi;
            *reinterpret_cast<short8v*>(&Ash[m_st][32 + kq * 8]) = lo;
        }
        {
            int nrow = bn + m_st;
            const uint4* g = reinterpret_cast<const uint4*>(&WTp[(size_t)nrow * K + k0 + kq * 8]);
            uint4 u0 = g[0], u1 = g[1];
            short8v hi, lo;
            unpack8(u0, u1, hi, lo);
            *reinterpret_cast<short8v*>(&Bsh[m_st][kq * 8])      = hi;
            *reinterpret_cast<short8v*>(&Bsh[m_st][32 + kq * 8]) = lo;
        }
        __syncthreads();

        short8v ah[2], al[2], bh[2], bl[2];
#pragma unroll
        for (int mi = 0; mi < 2; ++mi) {
            const unsigned short* p = &Ash[wm + mi * 16 + (lane & 15)][(lane >> 4) * 8];
            ah[mi] = *reinterpret_cast<const short8v*>(p);
            al[mi] = *reinterpret_cast<const short8v*>(p + 32);
        }
#pragma unroll
        for (int ni = 0; ni < 2; ++ni) {
            const unsigned short* p = &Bsh[wn + ni * 16 + (lane & 15)][(lane >> 4) * 8];
            bh[ni] = *reinterpret_cast<const short8v*>(p);
            bl[ni] = *reinterpret_cast<const short8v*>(p + 32);
        }
#pragma unroll
        for (int mi = 0; mi < 2; ++mi)
#pragma unroll
            for (int ni = 0; ni < 2; ++ni) {
                acc[mi][ni] = __builtin_amdgcn_mfma_f32_16x16x32_bf16(ah[mi], bh[ni], acc[mi][ni], 0, 0, 0);
                acc[mi][ni] = __builtin_amdgcn_mfma_f32_16x16x32_bf16(ah[mi], bl[ni], acc[mi][ni], 0, 0, 0);
                acc[mi][ni] = __builtin_amdgcn_mfma_f32_16x16x32_bf16(al[mi], bh[ni], acc[mi][ni], 0, 0, 0);
            }
        __syncthreads();
    }

    // epilogue: D row = (lane>>4)*4 + j, col = lane&15 (verified C/D mapping)
#pragma unroll
    for (int mi = 0; mi < 2; ++mi)
#pragma unroll
        for (int ni = 0; ni < 2; ++ni) {
            int colg = bn + wn + ni * 16 + (lane & 15);
            int rowb = bm + wm + mi * 16 + ((lane >> 4) << 2);
            float bv = 0.f;
            if constexpr (HAS_BIAS) bv = bias[colg];
#pragma unroll
            for (int j = 0; j < 4; ++j) {
                int row = rowb + j;
                if (row < M) {
                    float v = acc[mi][ni][j] + bv;
                    if constexpr (RELU) v = fmaxf(v, 0.f);
                    if constexpr (SCALE) v *= dscale[row];
                    if constexpr (PACK_OUT)
                        ((unsigned*)Cout)[(size_t)row * N + colg] = packsplit(v);
                    else if constexpr (F16_OUT)
                        ((__half*)Cout)[(size_t)row * N + colg] = __float2half(v);
                    else
                        ((float*)Cout)[(size_t)row * N + colg] = v;
                }
            }
        }
}

// ---------------- Aggregate (prescaled fp16 input h' = fp16(dinv .* h)):
// out_i = dinv_i * ( h'_i + sum_{s in N(i)} h'_s )  [+ bias]
// 4-deep unrolled gather, f32 accumulation.
template<int F, bool HAS_BIAS, bool PACK>
__global__ void k_aggregate(const __half* __restrict__ h, const float* __restrict__ bias,
                            const float* __restrict__ dinv, const int* __restrict__ rowoff,
                            const int* __restrict__ col, void* __restrict__ out, int n) {
    constexpr int VEC = F / 64;
    int lane = threadIdx.x & 63;
    int wid  = threadIdx.x >> 6;
    int node = blockIdx.x * 4 + wid;
    if (node >= n) return;
    float di = dinv[node];
    float acc[4][VEC];
#pragma unroll
    for (int b = 0; b < 4; ++b)
#pragma unroll
        for (int v = 0; v < VEC; ++v) acc[b][v] = 0.f;
    // self row into bank 0
    {
        const __half* ps = &h[(size_t)node * F + lane * VEC];
        if constexpr (VEC == 4) {
            uint2 u = *reinterpret_cast<const uint2*>(ps);
            acc[0][0] = h2f_lo(u.x); acc[0][1] = h2f_hi(u.x);
            acc[0][2] = h2f_lo(u.y); acc[0][3] = h2f_hi(u.y);
        } else if constexpr (VEC == 2) {
            unsigned u = *reinterpret_cast<const unsigned*>(ps);
            acc[0][0] = h2f_lo(u); acc[0][1] = h2f_hi(u);
        } else {
            acc[0][0] = __half2float(*ps);
        }
    }

    int e = rowoff[node], s1 = rowoff[node + 1];
    for (; e + 3 < s1; e += 4) {
        int s_0 = col[e], s_1 = col[e + 1], s_2 = col[e + 2], s_3 = col[e + 3];
        const __half* p0 = &h[(size_t)s_0 * F + lane * VEC];
        const __half* p1 = &h[(size_t)s_1 * F + lane * VEC];
        const __half* p2 = &h[(size_t)s_2 * F + lane * VEC];
        const __half* p3 = &h[(size_t)s_3 * F + lane * VEC];
        if constexpr (VEC == 4) {
            uint2 u0 = *reinterpret_cast<const uint2*>(p0);
            uint2 u1 = *reinterpret_cast<const uint2*>(p1);
            uint2 u2 = *reinterpret_cast<const uint2*>(p2);
            uint2 u3 = *reinterpret_cast<const uint2*>(p3);
            acc[0][0] += h2f_lo(u0.x); acc[0][1] += h2f_hi(u0.x);
            acc[0][2] += h2f_lo(u0.y); acc[0][3] += h2f_hi(u0.y);
            acc[1][0] += h2f_lo(u1.x); acc[1][1] += h2f_hi(u1.x);
            acc[1][2] += h2f_lo(u1.y); acc[1][3] += h2f_hi(u1.y);
            acc[2][0] += h2f_lo(u2.x); acc[2][1] += h2f_hi(u2.x);
            acc[2][2] += h2f_lo(u2.y); acc[2][3] += h2f_hi(u2.y);
            acc[3][0] += h2f_lo(u3.x); acc[3][1] += h2f_hi(u3.x);
            acc[3][2] += h2f_lo(u3.y); acc[3][3] += h2f_hi(u3.y);
        } else if constexpr (VEC == 2) {
            unsigned u0 = *reinterpret_cast<const unsigned*>(p0);
            unsigned u1 = *reinterpret_cast<const unsigned*>(p1);
            unsigned u2 = *reinterpret_cast<const unsigned*>(p2);
            unsigned u3 = *reinterpret_cast<const unsigned*>(p3);
            acc[0][0] += h2f_lo(u0); acc[0][1] += h2f_hi(u0);
            acc[1][0] += h2f_lo(u1); acc[1][1] += h2f_hi(u1);
            acc[2][0] += h2f_lo(u2); acc[2][1] += h2f_hi(u2);
            acc[3][0] += h2f_lo(u3); acc[3][1] += h2f_hi(u3);
        } else {
            acc[0][0] += __half2float(*p0); acc[1][0] += __half2float(*p1);
            acc[2][0] += __half2float(*p2); acc[3][0] += __half2float(*p3);
        }
    }
    for (; e < s1; ++e) {
        int s = col[e];
        const __half* ps = &h[(size_t)s * F + lane * VEC];
        if constexpr (VEC == 4) {
            uint2 u = *reinterpret_cast<const uint2*>(ps);
            acc[0][0] += h2f_lo(u.x); acc[0][1] += h2f_hi(u.x);
            acc[0][2] += h2f_lo(u.y); acc[0][3] += h2f_hi(u.y);
        } else if constexpr (VEC == 2) {
            unsigned u = *reinterpret_cast<const unsigned*>(ps);
            acc[0][0] += h2f_lo(u); acc[0][1] += h2f_hi(u);
        } else {
            acc[0][0] += __half2float(*ps);
        }
    }

    float r[VEC];
#pragma unroll
    for (int v = 0; v < VEC; ++v)
        r[v] = ((acc[0][v] + acc[1][v]) + (acc[2][v] + acc[3][v])) * di;
    if constexpr (HAS_BIAS) {
#pragma unroll
        for (int v = 0; v < VEC; ++v) r[v] += bias[lane * VEC + v];
    }

    if constexpr (PACK) {
        unsigned pv[VEC];
#pragma unroll
        for (int v = 0; v < VEC; ++v) pv[v] = packsplit(r[v]);
        unsigned* po = (unsigned*)out;
        if constexpr (VEC == 4)
            *reinterpret_cast<uint4*>(&po[(size_t)node * F + lane * 4]) =
                make_uint4(pv[0], pv[1], pv[2], pv[3]);
        else if constexpr (VEC == 2)
            *reinterpret_cast<uint2*>(&po[(size_t)node * F + lane * 2]) =
                make_uint2(pv[0], pv[1]);
        else
            po[(size_t)node * F + lane] = pv[0];
    } else {
        float* fo = (float*)out;
#pragma unroll
        for (int v = 0; v < VEC; ++v)
            fo[(size_t)node * F + lane * VEC + v] = r[v];
    }
}

// ---------------- Global mean pool (batch sorted) ----------------
__device__ __forceinline__ int lower_bound(const int* __restrict__ a, int n, int v) {
    int lo = 0, hi = n;
    while (lo < hi) {
        int mid = (lo + hi) >> 1;
        if (a[mid] < v) lo = mid + 1; else hi = mid;
    }
    return lo;
}

__global__ void k_pool(const float* __restrict__ h, const int* __restrict__ batch,
                       float* __restrict__ out, int n) {
    int g = blockIdx.x;
    int t = threadIdx.x;          // 256
    int fgrp = t & 15;            // float4 group
    int rgrp = t >> 4;            // 16 rows in flight
    int start = lower_bound(batch, n, g);
    int end   = lower_bound(batch, n, g + 1);
    float4 acc = make_float4(0.f, 0.f, 0.f, 0.f);
    for (int i = start + rgrp; i < end; i += 16) {
        float4 v = *reinterpret_cast<const float4*>(&h[(size_t)i * 64 + fgrp * 4]);
        acc.x += v.x; acc.y += v.y; acc.z += v.z; acc.w += v.w;
    }
    __shared__ float4 red[256];
    red[t] = acc;
    __syncthreads();
#pragma unroll
    for (int off = 8; off >= 1; off >>= 1) {
        if (rgrp < off) {
            float4 o = red[(rgrp + off) * 16 + fgrp];
            float4 m = red[t];
            m.x += o.x; m.y += o.y; m.z += o.z; m.w += o.w;
            red[t] = m;
        }
        __syncthreads();
    }
    if (rgrp == 0) {
        float denom = (float)max(end - start, 1);
        float4 m = red[fgrp];
        *reinterpret_cast<float4*>(&out[g * 64 + fgrp * 4]) =
            make_float4(m.x / denom, m.y / denom, m.z / denom, m.w / denom);
    }
}

// ---------------- Launch ----------------
extern "C" void kernel_launch(void* const* d_in, const int* in_sizes, int n_in,
                              void* d_out, int out_size, void* d_ws, size_t ws_size,
                              hipStream_t stream) {
    const float* x  = (const float*)d_in[0];
    const int* ei   = (const int*)d_in[1];
    const int* batch = (const int*)d_in[2];
    const float* W1 = (const float*)d_in[3]; const float* b1 = (const float*)d_in[4];
    const float* W2 = (const float*)d_in[5]; const float* b2 = (const float*)d_in[6];
    const float* W3 = (const float*)d_in[7]; const float* b3 = (const float*)d_in[8];
    float* out = (float*)d_out;

    const int n = in_sizes[0] / 128;
    const int E = in_sizes[1] / 2;
    const int* src = ei;
    const int* dst = ei + E;

    char* p = (char*)d_ws;
    auto carve = [&](size_t bytes) { char* q = p; p += (bytes + 255) & ~255ULL; return q; };
    char* R1      = carve((size_t)n * 256 * 4);   // 20MB multi-use
    char* R2      = carve((size_t)n * 256 * 4);   // 20MB multi-use
    float* dinv   = (float*)carve((size_t)n * 4);
    int*   cnt    = (int*)carve((size_t)n * 4);
    int*   rowoff = (int*)carve((size_t)(n + 1) * 4);
    int*   cursor = (int*)carve((size_t)n * 4);
    int*   col    = (int*)carve((size_t)E * 4);
    unsigned* W1T = (unsigned*)carve((size_t)256 * 128 * 4);
    unsigned* W2T = (unsigned*)carve((size_t)256 * 256 * 4);
    unsigned* W3T = (unsigned*)carve((size_t)64 * 256 * 4);

    // region aliases (lifetimes disjoint):
    __half*   XPh = (__half*)R2;                  // fp16(dinv.*x), [n][128], 5MB
    unsigned* P0  = (unsigned*)R1;                // agg0 out, packed [n][128], 10MB
    __half*   H1  = (__half*)R2;                  // gemm1 out (scaled), fp16 [n][256], 10MB (XPh dead)
    unsigned* P1  = (unsigned*)R1;                // agg1 out, packed [n][256], 20MB (P0 dead)
    unsigned* P2  = (unsigned*)R2;                // gemm2 out, packed [n][256], 20MB (H1 dead)
    __half*   T3  = (__half*)R1;                  // gemm3 out (scaled), fp16 [n][64], 2.5MB (P1 dead)
    float*    H3  = (float*)R2;                   // agg3 out, f32 [n][64], 5MB (P2 dead)

    hipMemsetAsync(cnt, 0, (size_t)n * 4, stream);
    k_count<<<(E + 255) / 256, 256, 0, stream>>>(dst, cnt, E);
    k_scan<<<1, 1024, 0, stream>>>(cnt, rowoff, cursor, dinv, n);
    k_fill<<<(E + 255) / 256, 256, 0, stream>>>(src, dst, cursor, col, E);
    k_split_w_all<<<(128*256 + 256*256 + 256*64 + 255) / 256, 256, 0, stream>>>(
        W1, W2, W3, W1T, W2T, W3T);

    const int mblocks = (n + 63) / 64;
    // layer 1: XPh = fp16(dinv.*x); agg0 = dinv.*(gather-sum XPh) [packed];
    //          H1 = fp16( relu(agg0@W1+b1) .* dinv )
    k_prescale<<<((n * 128 / 4) + 255) / 256, 256, 0, stream>>>(x, dinv, XPh, n * 128 / 4);
    k_aggregate<128, false, true><<<(n + 3) / 4, 256, 0, stream>>>(
        XPh, nullptr, dinv, rowoff, col, P0, n);
    k_gemm_mfma<true, true, true, false, true><<<dim3(4, mblocks), 256, 0, stream>>>(
        P0, W1T, b1, dinv, H1, n, 128, 256);
    // layer 2: agg1 = dinv.*(gather-sum H1) [packed]; P2 = packsplit(relu(agg1@W2+b2))
    k_aggregate<256, false, true><<<(n + 3) / 4, 256, 0, stream>>>(
        H1, nullptr, dinv, rowoff, col, P1, n);
    k_gemm_mfma<true, true, false, true, false><<<dim3(4, mblocks), 256, 0, stream>>>(
        P1, W2T, b2, nullptr, P2, n, 256, 256);
    // layer 3: T3 = fp16( (P2@W3) .* dinv ); H3 = dinv.*(gather-sum T3) + b3 [f32]
    k_gemm_mfma<false, false, true, false, true><<<dim3(1, mblocks), 256, 0, stream>>>(
        P2, W3T, nullptr, dinv, T3, n, 256, 64);
    k_aggregate<64, true, false><<<(n + 3) / 4, 256, 0, stream>>>(
        T3, b3, dinv, rowoff, col, H3, n);
    // pool
    k_pool<<<64, 256, 0, stream>>>(H3, batch, out, n);
}

// Round 9
// 193.632 us; speedup vs baseline: 1.9449x; 1.0198x over previous
//
#include <hip/hip_runtime.h>
#include <hip/hip_fp16.h>

typedef __attribute__((ext_vector_type(8))) short short8v;   // 8 bf16 (4 VGPR)
typedef __attribute__((ext_vector_type(4))) float f32x4;     // MFMA acc

// ---------------- bf16 split helpers ----------------
__device__ __forceinline__ unsigned short bf16_rne(float v) {
    unsigned b = __float_as_uint(v);
    b += 0x7fffu + ((b >> 16) & 1u);
    return (unsigned short)(b >> 16);
}
// pack v into (hi bf16 << 16) | lo bf16, v ~= hi + lo with ~2^-16 rel error
__device__ __forceinline__ unsigned packsplit(float v) {
    unsigned short hs = bf16_rne(v);
    float r = v - __uint_as_float(((unsigned)hs) << 16);
    unsigned short ls = bf16_rne(r);
    return (((unsigned)hs) << 16) | (unsigned)ls;
}
__device__ __forceinline__ float h2f_lo(unsigned u) {
    return __half2float(__ushort_as_half((unsigned short)(u & 0xffffu)));
}
__device__ __forceinline__ float h2f_hi(unsigned u) {
    return __half2float(__ushort_as_half((unsigned short)(u >> 16)));
}
__device__ __forceinline__ unsigned f2h_pack(float a, float b) {
    return (unsigned)__half_as_ushort(__float2half(a)) |
           ((unsigned)__half_as_ushort(__float2half(b)) << 16);
}

// ---------------- CSR build ----------------
__global__ void k_count(const int* __restrict__ dst, int* __restrict__ cnt, int E) {
    int e = blockIdx.x * blockDim.x + threadIdx.x;
    if (e < E) atomicAdd(&cnt[dst[e]], 1);
}

#define SCAN_CHUNK 20
__global__ void k_scan(const int* __restrict__ cnt, int* __restrict__ rowoff,
                       int* __restrict__ cursor, float* __restrict__ dinv, int n) {
    __shared__ int psum[1024];
    int t = threadIdx.x;
    int base = t * SCAN_CHUNK;
    int vals[SCAN_CHUNK];
    int local = 0;
#pragma unroll
    for (int i = 0; i < SCAN_CHUNK; ++i) {
        int idx = base + i;
        vals[i] = (idx < n) ? cnt[idx] : 0;
        local += vals[i];
    }
    psum[t] = local;
    __syncthreads();
    for (int off = 1; off < 1024; off <<= 1) {
        int v = 0;
        if (t >= off) v = psum[t - off];
        __syncthreads();
        if (t >= off) psum[t] += v;
        __syncthreads();
    }
    int run = (t > 0) ? psum[t - 1] : 0;
#pragma unroll
    for (int i = 0; i < SCAN_CHUNK; ++i) {
        int idx = base + i;
        if (idx < n) {
            rowoff[idx] = run;
            cursor[idx] = run;
            dinv[idx]   = rsqrtf((float)(vals[i] + 1));
            run += vals[i];
        }
    }
    if (t == 1023) rowoff[n] = psum[1023];
}

__global__ void k_fill(const int* __restrict__ src, const int* __restrict__ dst,
                       int* __restrict__ cursor, int* __restrict__ col, int E) {
    int e = blockIdx.x * blockDim.x + threadIdx.x;
    if (e < E) {
        int pos = atomicAdd(&cursor[dst[e]], 1);
        col[pos] = src[e];
    }
}

// ---------------- W pre-split (all 3 weights) + cnt zeroing (replaces memset) ----------------
__global__ void k_split_w_all(const float* __restrict__ W1, const float* __restrict__ W2,
                              const float* __restrict__ W3, unsigned* __restrict__ W1T,
                              unsigned* __restrict__ W2T, unsigned* __restrict__ W3T,
                              int* __restrict__ cnt, int n) {
    int e = blockIdx.x * 256 + threadIdx.x;
    if (e < n) cnt[e] = 0;   // fused zero: runs before k_count on the serial stream
    if (e < 128 * 256) {
        int k = e >> 8, nn = e & 255;
        W1T[(size_t)nn * 128 + k] = packsplit(W1[e]);
    } else if (e < 128 * 256 + 256 * 256) {
        int e2 = e - 128 * 256;
        int k = e2 >> 8, nn = e2 & 255;
        W2T[(size_t)nn * 256 + k] = packsplit(W2[e2]);
    } else if (e < 128 * 256 + 256 * 256 + 256 * 64) {
        int e3 = e - 128 * 256 - 256 * 256;
        int k = e3 >> 6, nn = e3 & 63;
        W3T[(size_t)nn * 256 + k] = packsplit(W3[e3]);
    }
}

// ---------------- x prescale: xp[r][c] = fp16( x[r][c] * dinv[r] ) ----------------
__global__ void k_prescale(const float* __restrict__ x, const float* __restrict__ dinv,
                           __half* __restrict__ xp, int total4 /* n*128/4 */) {
    int i = blockIdx.x * 256 + threadIdx.x;
    if (i >= total4) return;
    float4 v = reinterpret_cast<const float4*>(x)[i];
    float d = dinv[i >> 5];   // 32 float4 per 128-wide row
    reinterpret_cast<uint2*>(xp)[i] =
        make_uint2(f2h_pack(v.x * d, v.y * d), f2h_pack(v.z * d, v.w * d));
}

// ---------------- MFMA split-bf16 GEMM ----------------
// C[M,N] = A[M,K] @ W[K,N] (+bias, relu, *dinv[row]). A packed [M][K], WT packed [N][K].
// 64x64 tile, BK=32, 256 thr = 4 waves each 32x32 (2x2 of 16x16x32 MFMA).
__device__ __forceinline__ void unpack8(const uint4 u0, const uint4 u1,
                                        short8v& hi, short8v& lo) {
    unsigned av[8] = {u0.x, u0.y, u0.z, u0.w, u1.x, u1.y, u1.z, u1.w};
#pragma unroll
    for (int i = 0; i < 8; ++i) {
        hi[i] = (short)(av[i] >> 16);
        lo[i] = (short)(av[i] & 0xffffu);
    }
}

template<bool HAS_BIAS, bool RELU, bool SCALE, bool PACK_OUT, bool F16_OUT>
__global__ __launch_bounds__(256)
void k_gemm_mfma(const unsigned* __restrict__ Ap, const unsigned* __restrict__ WTp,
                 const float* __restrict__ bias, const float* __restrict__ dscale,
                 void* __restrict__ Cout, int M, int K, int N) {
    __shared__ __align__(16) unsigned short Ash[64][72];
    __shared__ __align__(16) unsigned short Bsh[64][72];
    const int tid = threadIdx.x;
    const int bm = blockIdx.y * 64, bn = blockIdx.x * 64;
    const int lane = tid & 63, w = tid >> 6;
    const int wm = (w >> 1) * 32, wn = (w & 1) * 32;
    const int m_st = tid >> 2, kq = tid & 3;   // staging: row, k-octet

    f32x4 acc[2][2];
#pragma unroll
    for (int i = 0; i < 2; ++i)
#pragma unroll
        for (int j = 0; j < 2; ++j) acc[i][j] = (f32x4){0.f, 0.f, 0.f, 0.f};

    for (int k0 = 0; k0 < K; k0 += 32) {
        {
            int row = bm + m_st;
            uint4 u0 = {0,0,0,0}, u1 = {0,0,0,0};
            if (row < M) {
                const uint4* g = reinterpret_cast<const uint4*>(&Ap[(size_t)row * K + k0 + kq * 8]);
                u0 = g[0]; u1 = g[1];
            }
            short8v hi, lo;
            unpack8(u0, u1, hi, lo);
            *reinterpret_cast<short8v*>(&Ash[m_st][kq * 8])      = hi;
            *reinterpret_cast<short8v*>(&Ash[m_st][32 + kq * 8]) = lo;
        }
        {
            int nrow = bn + m_st;
            const uint4* g = reinterpret_cast<const uint4*>(&WTp[(size_t)nrow * K + k0 + kq * 8]);
            uint4 u0 = g[0], u1 = g[1];
            short8v hi, lo;
            unpack8(u0, u1, hi, lo);
            *reinterpret_cast<short8v*>(&Bsh[m_st][kq * 8])      = hi;
            *reinterpret_cast<short8v*>(&Bsh[m_st][32 + kq * 8]) = lo;
        }
        __syncthreads();

        short8v ah[2], al[2], bh[2], bl[2];
#pragma unroll
        for (int mi = 0; mi < 2; ++mi) {
            const unsigned short* p = &Ash[wm + mi * 16 + (lane & 15)][(lane >> 4) * 8];
            ah[mi] = *reinterpret_cast<const short8v*>(p);
            al[mi] = *reinterpret_cast<const short8v*>(p + 32);
        }
#pragma unroll
        for (int ni = 0; ni < 2; ++ni) {
            const unsigned short* p = &Bsh[wn + ni * 16 + (lane & 15)][(lane >> 4) * 8];
            bh[ni] = *reinterpret_cast<const short8v*>(p);
            bl[ni] = *reinterpret_cast<const short8v*>(p + 32);
        }
#pragma unroll
        for (int mi = 0; mi < 2; ++mi)
#pragma unroll
            for (int ni = 0; ni < 2; ++ni) {
                acc[mi][ni] = __builtin_amdgcn_mfma_f32_16x16x32_bf16(ah[mi], bh[ni], acc[mi][ni], 0, 0, 0);
                acc[mi][ni] = __builtin_amdgcn_mfma_f32_16x16x32_bf16(ah[mi], bl[ni], acc[mi][ni], 0, 0, 0);
                acc[mi][ni] = __builtin_amdgcn_mfma_f32_16x16x32_bf16(al[mi], bh[ni], acc[mi][ni], 0, 0, 0);
            }
        __syncthreads();
    }

    // epilogue: D row = (lane>>4)*4 + j, col = lane&15 (verified C/D mapping)
#pragma unroll
    for (int mi = 0; mi < 2; ++mi)
#pragma unroll
        for (int ni = 0; ni < 2; ++ni) {
            int colg = bn + wn + ni * 16 + (lane & 15);
            int rowb = bm + wm + mi * 16 + ((lane >> 4) << 2);
            float bv = 0.f;
            if constexpr (HAS_BIAS) bv = bias[colg];
#pragma unroll
            for (int j = 0; j < 4; ++j) {
                int row = rowb + j;
                if (row < M) {
                    float v = acc[mi][ni][j] + bv;
                    if constexpr (RELU) v = fmaxf(v, 0.f);
                    if constexpr (SCALE) v *= dscale[row];
                    if constexpr (PACK_OUT)
                        ((unsigned*)Cout)[(size_t)row * N + colg] = packsplit(v);
                    else if constexpr (F16_OUT)
                        ((__half*)Cout)[(size_t)row * N + colg] = __float2half(v);
                    else
                        ((float*)Cout)[(size_t)row * N + colg] = v;
                }
            }
        }
}

// ---------------- Aggregate (prescaled fp16 input h' = fp16(dinv .* h)):
// out_i = dinv_i * ( h'_i + sum_{s in N(i)} h'_s )  [+ bias]
// 4-deep unrolled gather, f32 accumulation.
template<int F, bool HAS_BIAS, bool PACK>
__global__ void k_aggregate(const __half* __restrict__ h, const float* __restrict__ bias,
                            const float* __restrict__ dinv, const int* __restrict__ rowoff,
                            const int* __restrict__ col, void* __restrict__ out, int n) {
    constexpr int VEC = F / 64;
    int lane = threadIdx.x & 63;
    int wid  = threadIdx.x >> 6;
    int node = blockIdx.x * 4 + wid;
    if (node >= n) return;
    float di = dinv[node];
    float acc[4][VEC];
#pragma unroll
    for (int b = 0; b < 4; ++b)
#pragma unroll
        for (int v = 0; v < VEC; ++v) acc[b][v] = 0.f;
    // self row into bank 0
    {
        const __half* ps = &h[(size_t)node * F + lane * VEC];
        if constexpr (VEC == 4) {
            uint2 u = *reinterpret_cast<const uint2*>(ps);
            acc[0][0] = h2f_lo(u.x); acc[0][1] = h2f_hi(u.x);
            acc[0][2] = h2f_lo(u.y); acc[0][3] = h2f_hi(u.y);
        } else if constexpr (VEC == 2) {
            unsigned u = *reinterpret_cast<const unsigned*>(ps);
            acc[0][0] = h2f_lo(u); acc[0][1] = h2f_hi(u);
        } else {
            acc[0][0] = __half2float(*ps);
        }
    }

    int e = rowoff[node], s1 = rowoff[node + 1];
    for (; e + 3 < s1; e += 4) {
        int s_0 = col[e], s_1 = col[e + 1], s_2 = col[e + 2], s_3 = col[e + 3];
        const __half* p0 = &h[(size_t)s_0 * F + lane * VEC];
        const __half* p1 = &h[(size_t)s_1 * F + lane * VEC];
        const __half* p2 = &h[(size_t)s_2 * F + lane * VEC];
        const __half* p3 = &h[(size_t)s_3 * F + lane * VEC];
        if constexpr (VEC == 4) {
            uint2 u0 = *reinterpret_cast<const uint2*>(p0);
            uint2 u1 = *reinterpret_cast<const uint2*>(p1);
            uint2 u2 = *reinterpret_cast<const uint2*>(p2);
            uint2 u3 = *reinterpret_cast<const uint2*>(p3);
            acc[0][0] += h2f_lo(u0.x); acc[0][1] += h2f_hi(u0.x);
            acc[0][2] += h2f_lo(u0.y); acc[0][3] += h2f_hi(u0.y);
            acc[1][0] += h2f_lo(u1.x); acc[1][1] += h2f_hi(u1.x);
            acc[1][2] += h2f_lo(u1.y); acc[1][3] += h2f_hi(u1.y);
            acc[2][0] += h2f_lo(u2.x); acc[2][1] += h2f_hi(u2.x);
            acc[2][2] += h2f_lo(u2.y); acc[2][3] += h2f_hi(u2.y);
            acc[3][0] += h2f_lo(u3.x); acc[3][1] += h2f_hi(u3.x);
            acc[3][2] += h2f_lo(u3.y); acc[3][3] += h2f_hi(u3.y);
        } else if constexpr (VEC == 2) {
            unsigned u0 = *reinterpret_cast<const unsigned*>(p0);
            unsigned u1 = *reinterpret_cast<const unsigned*>(p1);
            unsigned u2 = *reinterpret_cast<const unsigned*>(p2);
            unsigned u3 = *reinterpret_cast<const unsigned*>(p3);
            acc[0][0] += h2f_lo(u0); acc[0][1] += h2f_hi(u0);
            acc[1][0] += h2f_lo(u1); acc[1][1] += h2f_hi(u1);
            acc[2][0] += h2f_lo(u2); acc[2][1] += h2f_hi(u2);
            acc[3][0] += h2f_lo(u3); acc[3][1] += h2f_hi(u3);
        } else {
            acc[0][0] += __half2float(*p0); acc[1][0] += __half2float(*p1);
            acc[2][0] += __half2float(*p2); acc[3][0] += __half2float(*p3);
        }
    }
    for (; e < s1; ++e) {
        int s = col[e];
        const __half* ps = &h[(size_t)s * F + lane * VEC];
        if constexpr (VEC == 4) {
            uint2 u = *reinterpret_cast<const uint2*>(ps);
            acc[0][0] += h2f_lo(u.x); acc[0][1] += h2f_hi(u.x);
            acc[0][2] += h2f_lo(u.y); acc[0][3] += h2f_hi(u.y);
        } else if constexpr (VEC == 2) {
            unsigned u = *reinterpret_cast<const unsigned*>(ps);
            acc[0][0] += h2f_lo(u); acc[0][1] += h2f_hi(u);
        } else {
            acc[0][0] += __half2float(*ps);
        }
    }

    float r[VEC];
#pragma unroll
    for (int v = 0; v < VEC; ++v)
        r[v] = ((acc[0][v] + acc[1][v]) + (acc[2][v] + acc[3][v])) * di;
    if constexpr (HAS_BIAS) {
#pragma unroll
        for (int v = 0; v < VEC; ++v) r[v] += bias[lane * VEC + v];
    }

    if constexpr (PACK) {
        unsigned pv[VEC];
#pragma unroll
        for (int v = 0; v < VEC; ++v) pv[v] = packsplit(r[v]);
        unsigned* po = (unsigned*)out;
        if constexpr (VEC == 4)
            *reinterpret_cast<uint4*>(&po[(size_t)node * F + lane * 4]) =
                make_uint4(pv[0], pv[1], pv[2], pv[3]);
        else if constexpr (VEC == 2)
            *reinterpret_cast<uint2*>(&po[(size_t)node * F + lane * 2]) =
                make_uint2(pv[0], pv[1]);
        else
            po[(size_t)node * F + lane] = pv[0];
    } else {
        float* fo = (float*)out;
#pragma unroll
        for (int v = 0; v < VEC; ++v)
            fo[(size_t)node * F + lane * VEC + v] = r[v];
    }
}

// ---------------- Global mean pool (batch sorted) ----------------
__device__ __forceinline__ int lower_bound(const int* __restrict__ a, int n, int v) {
    int lo = 0, hi = n;
    while (lo < hi) {
        int mid = (lo + hi) >> 1;
        if (a[mid] < v) lo = mid + 1; else hi = mid;
    }
    return lo;
}

__global__ void k_pool(const float* __restrict__ h, const int* __restrict__ batch,
                       float* __restrict__ out, int n) {
    int g = blockIdx.x;
    int t = threadIdx.x;          // 256
    int fgrp = t & 15;            // float4 group
    int rgrp = t >> 4;            // 16 rows in flight
    int start = lower_bound(batch, n, g);
    int end   = lower_bound(batch, n, g + 1);
    float4 acc = make_float4(0.f, 0.f, 0.f, 0.f);
    for (int i = start + rgrp; i < end; i += 16) {
        float4 v = *reinterpret_cast<const float4*>(&h[(size_t)i * 64 + fgrp * 4]);
        acc.x += v.x; acc.y += v.y; acc.z += v.z; acc.w += v.w;
    }
    __shared__ float4 red[256];
    red[t] = acc;
    __syncthreads();
#pragma unroll
    for (int off = 8; off >= 1; off >>= 1) {
        if (rgrp < off) {
            float4 o = red[(rgrp + off) * 16 + fgrp];
            float4 m = red[t];
            m.x += o.x; m.y += o.y; m.z += o.z; m.w += o.w;
            red[t] = m;
        }
        __syncthreads();
    }
    if (rgrp == 0) {
        float denom = (float)max(end - start, 1);
        float4 m = red[fgrp];
        *reinterpret_cast<float4*>(&out[g * 64 + fgrp * 4]) =
            make_float4(m.x / denom, m.y / denom, m.z / denom, m.w / denom);
    }
}

// ---------------- Launch ----------------
extern "C" void kernel_launch(void* const* d_in, const int* in_sizes, int n_in,
                              void* d_out, int out_size, void* d_ws, size_t ws_size,
                              hipStream_t stream) {
    const float* x  = (const float*)d_in[0];
    const int* ei   = (const int*)d_in[1];
    const int* batch = (const int*)d_in[2];
    const float* W1 = (const float*)d_in[3]; const float* b1 = (const float*)d_in[4];
    const float* W2 = (const float*)d_in[5]; const float* b2 = (const float*)d_in[6];
    const float* W3 = (const float*)d_in[7]; const float* b3 = (const float*)d_in[8];
    float* out = (float*)d_out;

    const int n = in_sizes[0] / 128;
    const int E = in_sizes[1] / 2;
    const int* src = ei;
    const int* dst = ei + E;

    char* p = (char*)d_ws;
    auto carve = [&](size_t bytes) { char* q = p; p += (bytes + 255) & ~255ULL; return q; };
    char* R1      = carve((size_t)n * 256 * 4);   // 20MB multi-use
    char* R2      = carve((size_t)n * 256 * 4);   // 20MB multi-use
    float* dinv   = (float*)carve((size_t)n * 4);
    int*   cnt    = (int*)carve((size_t)n * 4);
    int*   rowoff = (int*)carve((size_t)(n + 1) * 4);
    int*   cursor = (int*)carve((size_t)n * 4);
    int*   col    = (int*)carve((size_t)E * 4);
    unsigned* W1T = (unsigned*)carve((size_t)256 * 128 * 4);
    unsigned* W2T = (unsigned*)carve((size_t)256 * 256 * 4);
    unsigned* W3T = (unsigned*)carve((size_t)64 * 256 * 4);

    // region aliases (lifetimes disjoint):
    __half*   XPh = (__half*)R2;                  // fp16(dinv.*x), [n][128], 5MB
    unsigned* P0  = (unsigned*)R1;                // agg0 out, packed [n][128], 10MB
    __half*   H1  = (__half*)R2;                  // gemm1 out (scaled), fp16 [n][256], 10MB (XPh dead)
    unsigned* P1  = (unsigned*)R1;                // agg1 out, packed [n][256], 20MB (P0 dead)
    unsigned* P2  = (unsigned*)R2;                // gemm2 out, packed [n][256], 20MB (H1 dead)
    __half*   T3  = (__half*)R1;                  // gemm3 out (scaled), fp16 [n][64], 2.5MB (P1 dead)
    float*    H3  = (float*)R2;                   // agg3 out, f32 [n][64], 5MB (P2 dead)

    // split_w first: fuses cnt zeroing (replaces the 41us runtime fill kernel)
    k_split_w_all<<<(128*256 + 256*256 + 256*64 + 255) / 256, 256, 0, stream>>>(
        W1, W2, W3, W1T, W2T, W3T, cnt, n);
    k_count<<<(E + 255) / 256, 256, 0, stream>>>(dst, cnt, E);
    k_scan<<<1, 1024, 0, stream>>>(cnt, rowoff, cursor, dinv, n);
    k_fill<<<(E + 255) / 256, 256, 0, stream>>>(src, dst, cursor, col, E);

    const int mblocks = (n + 63) / 64;
    // layer 1: XPh = fp16(dinv.*x); agg0 = dinv.*(gather-sum XPh) [packed];
    //          H1 = fp16( relu(agg0@W1+b1) .* dinv )
    k_prescale<<<((n * 128 / 4) + 255) / 256, 256, 0, stream>>>(x, dinv, XPh, n * 128 / 4);
    k_aggregate<128, false, true><<<(n + 3) / 4, 256, 0, stream>>>(
        XPh, nullptr, dinv, rowoff, col, P0, n);
    k_gemm_mfma<true, true, true, false, true><<<dim3(4, mblocks), 256, 0, stream>>>(
        P0, W1T, b1, dinv, H1, n, 128, 256);
    // layer 2: agg1 = dinv.*(gather-sum H1) [packed]; P2 = packsplit(relu(agg1@W2+b2))
    k_aggregate<256, false, true><<<(n + 3) / 4, 256, 0, stream>>>(
        H1, nullptr, dinv, rowoff, col, P1, n);
    k_gemm_mfma<true, true, false, true, false><<<dim3(4, mblocks), 256, 0, stream>>>(
        P1, W2T, b2, nullptr, P2, n, 256, 256);
    // layer 3: T3 = fp16( (P2@W3) .* dinv ); H3 = dinv.*(gather-sum T3) + b3 [f32]
    k_gemm_mfma<false, false, true, false, true><<<dim3(1, mblocks), 256, 0, stream>>>(
        P2, W3T, nullptr, dinv, T3, n, 256, 64);
    k_aggregate<64, true, false><<<(n + 3) / 4, 256, 0, stream>>>(
        T3, b3, dinv, rowoff, col, H3, n);
    // pool
    k_pool<<<64, 256, 0, stream>>>(H3, batch, out, n);
}

// Round 10
// 187.444 us; speedup vs baseline: 2.0091x; 1.0330x over previous
//
#include <hip/hip_runtime.h>
#include <hip/hip_fp16.h>

typedef __attribute__((ext_vector_type(8))) short short8v;       // 8 x 16-bit lanes
typedef __attribute__((ext_vector_type(8))) _Float16 half8v;     // MFMA f16 A/B frag
typedef __attribute__((ext_vector_type(4))) float f32x4;         // MFMA acc

// ---------------- f16 helpers ----------------
__device__ __forceinline__ float h2f_lo(unsigned u) {
    return __half2float(__ushort_as_half((unsigned short)(u & 0xffffu)));
}
__device__ __forceinline__ float h2f_hi(unsigned u) {
    return __half2float(__ushort_as_half((unsigned short)(u >> 16)));
}
__device__ __forceinline__ unsigned f2h_pack(float a, float b) {
    return (unsigned)__half_as_ushort(__float2half(a)) |
           ((unsigned)__half_as_ushort(__float2half(b)) << 16);
}
// split w into f16 hi + f16 lo (w ~= hi + lo, rep err ~2^-24): packed (hi<<16)|lo
__device__ __forceinline__ unsigned packsplit_f16(float v) {
    unsigned short hs = __half_as_ushort(__float2half(v));
    float r = v - __half2float(__ushort_as_half(hs));
    unsigned short ls = __half_as_ushort(__float2half(r));
    return (((unsigned)hs) << 16) | (unsigned)ls;
}

// ---------------- CSR build ----------------
__global__ void k_count(const int* __restrict__ dst, int* __restrict__ cnt, int E) {
    int e = blockIdx.x * blockDim.x + threadIdx.x;
    if (e < E) atomicAdd(&cnt[dst[e]], 1);
}

// 1 block x 1024 threads; shfl wave-scan (2 barriers).
#define SCAN_CHUNK 20
__global__ void k_scan(const int* __restrict__ cnt, int* __restrict__ rowoff,
                       int* __restrict__ cursor, float* __restrict__ dinv, int n) {
    __shared__ int wsum[16];
    int t = threadIdx.x;
    int base = t * SCAN_CHUNK;
    int vals[SCAN_CHUNK];
    int local = 0;
#pragma unroll
    for (int i = 0; i < SCAN_CHUNK; ++i) {
        int idx = base + i;
        vals[i] = (idx < n) ? cnt[idx] : 0;
        local += vals[i];
    }
    int lane = t & 63, wv = t >> 6;
    int incl = local;
#pragma unroll
    for (int off = 1; off < 64; off <<= 1) {
        int u = __shfl_up(incl, off, 64);
        if (lane >= off) incl += u;
    }
    if (lane == 63) wsum[wv] = incl;
    __syncthreads();
    if (t == 0) {
        int run = 0;
#pragma unroll
        for (int i = 0; i < 16; ++i) { int v = wsum[i]; wsum[i] = run; run += v; }
    }
    __syncthreads();
    int run = wsum[wv] + incl - local;   // exclusive prefix for this thread's chunk
#pragma unroll
    for (int i = 0; i < SCAN_CHUNK; ++i) {
        int idx = base + i;
        if (idx < n) {
            rowoff[idx] = run;
            cursor[idx] = run;
            dinv[idx]   = rsqrtf((float)(vals[i] + 1));
            run += vals[i];
        }
    }
    if (t == 1023) rowoff[n] = run;      // = grand total
}

__global__ void k_fill(const int* __restrict__ src, const int* __restrict__ dst,
                       int* __restrict__ cursor, int* __restrict__ col, int E) {
    int e = blockIdx.x * blockDim.x + threadIdx.x;
    if (e < E) {
        int pos = atomicAdd(&cursor[dst[e]], 1);
        col[pos] = src[e];
    }
}

// ---------------- W pre-split to f16 hi/lo (all 3 weights) + cnt zeroing ----------------
__global__ void k_split_w_all(const float* __restrict__ W1, const float* __restrict__ W2,
                              const float* __restrict__ W3, unsigned* __restrict__ W1T,
                              unsigned* __restrict__ W2T, unsigned* __restrict__ W3T,
                              int* __restrict__ cnt, int n) {
    int e = blockIdx.x * 256 + threadIdx.x;
    if (e < n) cnt[e] = 0;   // fused zero: runs before k_count on the serial stream
    if (e < 128 * 256) {
        int k = e >> 8, nn = e & 255;
        W1T[(size_t)nn * 128 + k] = packsplit_f16(W1[e]);
    } else if (e < 128 * 256 + 256 * 256) {
        int e2 = e - 128 * 256;
        int k = e2 >> 8, nn = e2 & 255;
        W2T[(size_t)nn * 256 + k] = packsplit_f16(W2[e2]);
    } else if (e < 128 * 256 + 256 * 256 + 256 * 64) {
        int e3 = e - 128 * 256 - 256 * 256;
        int k = e3 >> 6, nn = e3 & 63;
        W3T[(size_t)nn * 256 + k] = packsplit_f16(W3[e3]);
    }
}

// ---------------- x prescale: xp[r][c] = fp16( x[r][c] * dinv[r] ) ----------------
__global__ void k_prescale(const float* __restrict__ x, const float* __restrict__ dinv,
                           __half* __restrict__ xp, int total4 /* n*128/4 */) {
    int i = blockIdx.x * 256 + threadIdx.x;
    if (i >= total4) return;
    float4 v = reinterpret_cast<const float4*>(x)[i];
    float d = dinv[i >> 5];   // 32 float4 per 128-wide row
    reinterpret_cast<uint2*>(xp)[i] =
        make_uint2(f2h_pack(v.x * d, v.y * d), f2h_pack(v.z * d, v.w * d));
}

// ---------------- MFMA f16 GEMM ----------------
// C[M,N] = A[M,K] @ W[K,N] (+bias, relu, *dinv[row]); A fp16 [M][K], WT f16-split [N][K].
// 64x64 tile, BK=32, 256 thr = 4 waves each 32x32 (2x2 of 16x16x32 MFMA).
// Per fragment pair: 2 MFMA (a*wh + a*wl).
__device__ __forceinline__ void unpack8(const uint4 u0, const uint4 u1,
                                        short8v& hi, short8v& lo) {
    unsigned av[8] = {u0.x, u0.y, u0.z, u0.w, u1.x, u1.y, u1.z, u1.w};
#pragma unroll
    for (int i = 0; i < 8; ++i) {
        hi[i] = (short)(av[i] >> 16);
        lo[i] = (short)(av[i] & 0xffffu);
    }
}

template<bool HAS_BIAS, bool RELU, bool SCALE>
__global__ __launch_bounds__(256)
void k_gemm_f16(const __half* __restrict__ Ah, const unsigned* __restrict__ WTp,
                const float* __restrict__ bias, const float* __restrict__ dscale,
                __half* __restrict__ Cout, int M, int K, int N) {
    // 144B row stride (16B-aligned writes, 2-way-max bank aliasing on b128 frag reads)
    __shared__ __align__(16) _Float16      Ash[64][72];  // cols 0..31 used
    __shared__ __align__(16) unsigned short Bsh[64][72]; // hi 0..31 | lo 32..63
    const int tid = threadIdx.x;
    const int bm = blockIdx.y * 64, bn = blockIdx.x * 64;
    const int lane = tid & 63, w = tid >> 6;
    const int wm = (w >> 1) * 32, wn = (w & 1) * 32;
    const int m_st = tid >> 2, kq = tid & 3;   // staging: row, k-octet

    f32x4 acc[2][2];
#pragma unroll
    for (int i = 0; i < 2; ++i)
#pragma unroll
        for (int j = 0; j < 2; ++j) acc[i][j] = (f32x4){0.f, 0.f, 0.f, 0.f};

    for (int k0 = 0; k0 < K; k0 += 32) {
        {   // A tile: 16B (8 fp16) per thread, direct copy, no unpack
            int row = bm + m_st;
            uint4 u = {0, 0, 0, 0};
            if (row < M)
                u = *reinterpret_cast<const uint4*>(&Ah[(size_t)row * K + k0 + kq * 8]);
            *reinterpret_cast<uint4*>(&Ash[m_st][kq * 8]) = u;
        }
        {   // B tile: unpack f16 hi/lo planes
            int nrow = bn + m_st;
            const uint4* g = reinterpret_cast<const uint4*>(&WTp[(size_t)nrow * K + k0 + kq * 8]);
            uint4 u0 = g[0], u1 = g[1];
            short8v hi, lo;
            unpack8(u0, u1, hi, lo);
            *reinterpret_cast<short8v*>(&Bsh[m_st][kq * 8])      = hi;
            *reinterpret_cast<short8v*>(&Bsh[m_st][32 + kq * 8]) = lo;
        }
        __syncthreads();

        half8v a[2], bh[2], bl[2];
#pragma unroll
        for (int mi = 0; mi < 2; ++mi)
            a[mi] = *reinterpret_cast<const half8v*>(&Ash[wm + mi * 16 + (lane & 15)][(lane >> 4) * 8]);
#pragma unroll
        for (int ni = 0; ni < 2; ++ni) {
            const unsigned short* p = &Bsh[wn + ni * 16 + (lane & 15)][(lane >> 4) * 8];
            bh[ni] = *reinterpret_cast<const half8v*>(p);
            bl[ni] = *reinterpret_cast<const half8v*>(p + 32);
        }
#pragma unroll
        for (int mi = 0; mi < 2; ++mi)
#pragma unroll
            for (int ni = 0; ni < 2; ++ni) {
                acc[mi][ni] = __builtin_amdgcn_mfma_f32_16x16x32_f16(a[mi], bh[ni], acc[mi][ni], 0, 0, 0);
                acc[mi][ni] = __builtin_amdgcn_mfma_f32_16x16x32_f16(a[mi], bl[ni], acc[mi][ni], 0, 0, 0);
            }
        __syncthreads();
    }

    // epilogue: D row = (lane>>4)*4 + j, col = lane&15 (verified C/D mapping)
#pragma unroll
    for (int mi = 0; mi < 2; ++mi)
#pragma unroll
        for (int ni = 0; ni < 2; ++ni) {
            int colg = bn + wn + ni * 16 + (lane & 15);
            int rowb = bm + wm + mi * 16 + ((lane >> 4) << 2);
            float bv = 0.f;
            if constexpr (HAS_BIAS) bv = bias[colg];
#pragma unroll
            for (int j = 0; j < 4; ++j) {
                int row = rowb + j;
                if (row < M) {
                    float v = acc[mi][ni][j] + bv;
                    if constexpr (RELU) v = fmaxf(v, 0.f);
                    if constexpr (SCALE) v *= dscale[row];
                    Cout[(size_t)row * N + colg] = __float2half(v);
                }
            }
        }
}

// ---------------- Aggregate (prescaled fp16 input h' = fp16(dinv .* h)):
// out_i = dinv_i * ( h'_i + sum_{s in N(i)} h'_s )  [+ bias]; f32 accum, 4 banks.
// Output: fp16 (F16OUT) or f32.
template<int F, bool HAS_BIAS, bool F16OUT>
__global__ void k_aggregate(const __half* __restrict__ h, const float* __restrict__ bias,
                            const float* __restrict__ dinv, const int* __restrict__ rowoff,
                            const int* __restrict__ col, void* __restrict__ out, int n) {
    constexpr int VEC = F / 64;
    int lane = threadIdx.x & 63;
    int wid  = threadIdx.x >> 6;
    int node = blockIdx.x * 4 + wid;
    if (node >= n) return;
    float di = dinv[node];
    float acc[4][VEC];
#pragma unroll
    for (int b = 0; b < 4; ++b)
#pragma unroll
        for (int v = 0; v < VEC; ++v) acc[b][v] = 0.f;
    // self row into bank 0
    {
        const __half* ps = &h[(size_t)node * F + lane * VEC];
        if constexpr (VEC == 4) {
            uint2 u = *reinterpret_cast<const uint2*>(ps);
            acc[0][0] = h2f_lo(u.x); acc[0][1] = h2f_hi(u.x);
            acc[0][2] = h2f_lo(u.y); acc[0][3] = h2f_hi(u.y);
        } else if constexpr (VEC == 2) {
            unsigned u = *reinterpret_cast<const unsigned*>(ps);
            acc[0][0] = h2f_lo(u); acc[0][1] = h2f_hi(u);
        } else {
            acc[0][0] = __half2float(*ps);
        }
    }

    int e = rowoff[node], s1 = rowoff[node + 1];
    for (; e + 3 < s1; e += 4) {
        int s_0 = col[e], s_1 = col[e + 1], s_2 = col[e + 2], s_3 = col[e + 3];
        const __half* p0 = &h[(size_t)s_0 * F + lane * VEC];
        const __half* p1 = &h[(size_t)s_1 * F + lane * VEC];
        const __half* p2 = &h[(size_t)s_2 * F + lane * VEC];
        const __half* p3 = &h[(size_t)s_3 * F + lane * VEC];
        if constexpr (VEC == 4) {
            uint2 u0 = *reinterpret_cast<const uint2*>(p0);
            uint2 u1 = *reinterpret_cast<const uint2*>(p1);
            uint2 u2 = *reinterpret_cast<const uint2*>(p2);
            uint2 u3 = *reinterpret_cast<const uint2*>(p3);
            acc[0][0] += h2f_lo(u0.x); acc[0][1] += h2f_hi(u0.x);
            acc[0][2] += h2f_lo(u0.y); acc[0][3] += h2f_hi(u0.y);
            acc[1][0] += h2f_lo(u1.x); acc[1][1] += h2f_hi(u1.x);
            acc[1][2] += h2f_lo(u1.y); acc[1][3] += h2f_hi(u1.y);
            acc[2][0] += h2f_lo(u2.x); acc[2][1] += h2f_hi(u2.x);
            acc[2][2] += h2f_lo(u2.y); acc[2][3] += h2f_hi(u2.y);
            acc[3][0] += h2f_lo(u3.x); acc[3][1] += h2f_hi(u3.x);
            acc[3][2] += h2f_lo(u3.y); acc[3][3] += h2f_hi(u3.y);
        } else if constexpr (VEC == 2) {
            unsigned u0 = *reinterpret_cast<const unsigned*>(p0);
            unsigned u1 = *reinterpret_cast<const unsigned*>(p1);
            unsigned u2 = *reinterpret_cast<const unsigned*>(p2);
            unsigned u3 = *reinterpret_cast<const unsigned*>(p3);
            acc[0][0] += h2f_lo(u0); acc[0][1] += h2f_hi(u0);
            acc[1][0] += h2f_lo(u1); acc[1][1] += h2f_hi(u1);
            acc[2][0] += h2f_lo(u2); acc[2][1] += h2f_hi(u2);
            acc[3][0] += h2f_lo(u3); acc[3][1] += h2f_hi(u3);
        } else {
            acc[0][0] += __half2float(*p0); acc[1][0] += __half2float(*p1);
            acc[2][0] += __half2float(*p2); acc[3][0] += __half2float(*p3);
        }
    }
    for (; e < s1; ++e) {
        int s = col[e];
        const __half* ps = &h[(size_t)s * F + lane * VEC];
        if constexpr (VEC == 4) {
            uint2 u = *reinterpret_cast<const uint2*>(ps);
            acc[0][0] += h2f_lo(u.x); acc[0][1] += h2f_hi(u.x);
            acc[0][2] += h2f_lo(u.y); acc[0][3] += h2f_hi(u.y);
        } else if constexpr (VEC == 2) {
            unsigned u = *reinterpret_cast<const unsigned*>(ps);
            acc[0][0] += h2f_lo(u); acc[0][1] += h2f_hi(u);
        } else {
            acc[0][0] += __half2float(*ps);
        }
    }

    float r[VEC];
#pragma unroll
    for (int v = 0; v < VEC; ++v)
        r[v] = ((acc[0][v] + acc[1][v]) + (acc[2][v] + acc[3][v])) * di;
    if constexpr (HAS_BIAS) {
#pragma unroll
        for (int v = 0; v < VEC; ++v) r[v] += bias[lane * VEC + v];
    }

    if constexpr (F16OUT) {
        unsigned* po = (unsigned*)out;
        if constexpr (VEC == 4)
            *reinterpret_cast<uint2*>(&po[(size_t)node * (F / 2) + lane * 2]) =
                make_uint2(f2h_pack(r[0], r[1]), f2h_pack(r[2], r[3]));
        else if constexpr (VEC == 2)
            po[(size_t)node * (F / 2) + lane] = f2h_pack(r[0], r[1]);
        else
            ((__half*)out)[(size_t)node * F + lane] = __float2half(r[0]);
    } else {
        float* fo = (float*)out;
#pragma unroll
        for (int v = 0; v < VEC; ++v)
            fo[(size_t)node * F + lane * VEC + v] = r[v];
    }
}

// ---------------- Global mean pool (batch sorted) ----------------
__device__ __forceinline__ int lower_bound(const int* __restrict__ a, int n, int v) {
    int lo = 0, hi = n;
    while (lo < hi) {
        int mid = (lo + hi) >> 1;
        if (a[mid] < v) lo = mid + 1; else hi = mid;
    }
    return lo;
}

__global__ void k_pool(const float* __restrict__ h, const int* __restrict__ batch,
                       float* __restrict__ out, int n) {
    int g = blockIdx.x;
    int t = threadIdx.x;          // 256
    int fgrp = t & 15;            // float4 group
    int rgrp = t >> 4;            // 16 rows in flight
    int start = lower_bound(batch, n, g);
    int end   = lower_bound(batch, n, g + 1);
    float4 acc = make_float4(0.f, 0.f, 0.f, 0.f);
    for (int i = start + rgrp; i < end; i += 16) {
        float4 v = *reinterpret_cast<const float4*>(&h[(size_t)i * 64 + fgrp * 4]);
        acc.x += v.x; acc.y += v.y; acc.z += v.z; acc.w += v.w;
    }
    __shared__ float4 red[256];
    red[t] = acc;
    __syncthreads();
#pragma unroll
    for (int off = 8; off >= 1; off >>= 1) {
        if (rgrp < off) {
            float4 o = red[(rgrp + off) * 16 + fgrp];
            float4 m = red[t];
            m.x += o.x; m.y += o.y; m.z += o.z; m.w += o.w;
            red[t] = m;
        }
        __syncthreads();
    }
    if (rgrp == 0) {
        float denom = (float)max(end - start, 1);
        float4 m = red[fgrp];
        *reinterpret_cast<float4*>(&out[g * 64 + fgrp * 4]) =
            make_float4(m.x / denom, m.y / denom, m.z / denom, m.w / denom);
    }
}

// ---------------- Launch ----------------
extern "C" void kernel_launch(void* const* d_in, const int* in_sizes, int n_in,
                              void* d_out, int out_size, void* d_ws, size_t ws_size,
                              hipStream_t stream) {
    const float* x  = (const float*)d_in[0];
    const int* ei   = (const int*)d_in[1];
    const int* batch = (const int*)d_in[2];
    const float* W1 = (const float*)d_in[3]; const float* b1 = (const float*)d_in[4];
    const float* W2 = (const float*)d_in[5]; const float* b2 = (const float*)d_in[6];
    const float* W3 = (const float*)d_in[7]; const float* b3 = (const float*)d_in[8];
    float* out = (float*)d_out;

    const int n = in_sizes[0] / 128;
    const int E = in_sizes[1] / 2;
    const int* src = ei;
    const int* dst = ei + E;

    char* p = (char*)d_ws;
    auto carve = [&](size_t bytes) { char* q = p; p += (bytes + 255) & ~255ULL; return q; };
    char* R1      = carve((size_t)n * 256 * 4);   // 20MB multi-use
    char* R2      = carve((size_t)n * 256 * 4);   // 20MB multi-use
    float* dinv   = (float*)carve((size_t)n * 4);
    int*   cnt    = (int*)carve((size_t)n * 4);
    int*   rowoff = (int*)carve((size_t)(n + 1) * 4);
    int*   cursor = (int*)carve((size_t)n * 4);
    int*   col    = (int*)carve((size_t)E * 4);
    unsigned* W1T = (unsigned*)carve((size_t)256 * 128 * 4);
    unsigned* W2T = (unsigned*)carve((size_t)256 * 256 * 4);
    unsigned* W3T = (unsigned*)carve((size_t)64 * 256 * 4);

    // region aliases (lifetimes disjoint):
    __half*   XPh = (__half*)R2;                  // fp16(dinv.*x), [n][128], 5MB
    __half*   A0  = (__half*)R1;                  // agg0 out, fp16 [n][128], 5MB
    __half*   H1  = (__half*)R2;                  // gemm1 out (scaled), fp16 [n][256], 10MB (XPh dead)
    __half*   A1  = (__half*)R1;                  // agg1 out, fp16 [n][256], 10MB (A0 dead)
    __half*   P2  = (__half*)R2;                  // gemm2 out, fp16 [n][256], 10MB (H1 dead)
    __half*   T3  = (__half*)R1;                  // gemm3 out (scaled), fp16 [n][64], 2.5MB (A1 dead)
    float*    H3  = (float*)R2;                   // agg3 out, f32 [n][64], 5MB (P2 dead)

    // split_w first: fuses cnt zeroing
    k_split_w_all<<<(128*256 + 256*256 + 256*64 + 255) / 256, 256, 0, stream>>>(
        W1, W2, W3, W1T, W2T, W3T, cnt, n);
    k_count<<<(E + 255) / 256, 256, 0, stream>>>(dst, cnt, E);
    k_scan<<<1, 1024, 0, stream>>>(cnt, rowoff, cursor, dinv, n);
    k_fill<<<(E + 255) / 256, 256, 0, stream>>>(src, dst, cursor, col, E);

    const int mblocks = (n + 63) / 64;
    // layer 1: XPh = fp16(dinv.*x); A0 = fp16(dinv.*(gather-sum XPh));
    //          H1 = fp16( relu(A0@W1+b1) .* dinv )
    k_prescale<<<((n * 128 / 4) + 255) / 256, 256, 0, stream>>>(x, dinv, XPh, n * 128 / 4);
    k_aggregate<128, false, true><<<(n + 3) / 4, 256, 0, stream>>>(
        XPh, nullptr, dinv, rowoff, col, A0, n);
    k_gemm_f16<true, true, true><<<dim3(4, mblocks), 256, 0, stream>>>(
        A0, W1T, b1, dinv, H1, n, 128, 256);
    // layer 2: A1 = fp16(dinv.*(gather-sum H1)); P2 = fp16(relu(A1@W2+b2))
    k_aggregate<256, false, true><<<(n + 3) / 4, 256, 0, stream>>>(
        H1, nullptr, dinv, rowoff, col, A1, n);
    k_gemm_f16<true, true, false><<<dim3(4, mblocks), 256, 0, stream>>>(
        A1, W2T, b2, nullptr, P2, n, 256, 256);
    // layer 3: T3 = fp16( (P2@W3) .* dinv ); H3 = dinv.*(gather-sum T3) + b3 [f32]
    k_gemm_f16<false, false, true><<<dim3(1, mblocks), 256, 0, stream>>>(
        P2, W3T, nullptr, dinv, T3, n, 256, 64);
    k_aggregate<64, true, false><<<(n + 3) / 4, 256, 0, stream>>>(
        T3, b3, dinv, rowoff, col, H3, n);
    // pool
    k_pool<<<64, 256, 0, stream>>>(H3, batch, out, n);
}